// Round 2
// baseline (2163.403 us; speedup 1.0000x reference)
//
#include <hip/hip_runtime.h>
#include <math.h>

#define BB 16
#define PP 1000
#define NN 1000

static __device__ __forceinline__ int imin(int a, int b) { return a < b ? a : b; }

// ---------------------------------------------------------------------------
// GEMM: C[M x 256] = A[M x 256] @ W[256 x 256]  (M = 16000)
// MODE 0: plain   MODE 1: += ex1[row] * ex2[col]  (q rank-1 from attr)
// MODE 2: += ex2[col]  (bias)
// 64x64 tile, K-chunks of 16, 4x4 microtile, transposed-A LDS.
// ---------------------------------------------------------------------------
template <int MODE>
__global__ __launch_bounds__(256) void gemm256_kernel(
    const float* __restrict__ A, const float* __restrict__ W,
    float* __restrict__ C, const float* __restrict__ ex1,
    const float* __restrict__ ex2) {
  __shared__ float At[16][68];
  __shared__ float Ws[16][68];
  const int t = threadIdx.x;
  const int tx = t & 15, ty = t >> 4;
  const int row0 = blockIdx.y * 64, col0 = blockIdx.x * 64;
  const int ar = t >> 2, akq = t & 3;   // A load: row, k-quad
  const int wr = t >> 4, wc = t & 15;   // W load: k-row, col-quad
  float c[4][4] = {};
  for (int kc = 0; kc < 16; ++kc) {
    const float4 av =
        *(const float4*)&A[(size_t)(row0 + ar) * 256 + kc * 16 + akq * 4];
    const float4 wv =
        *(const float4*)&W[(size_t)(kc * 16 + wr) * 256 + col0 + wc * 4];
    At[akq * 4 + 0][ar] = av.x;
    At[akq * 4 + 1][ar] = av.y;
    At[akq * 4 + 2][ar] = av.z;
    At[akq * 4 + 3][ar] = av.w;
    *(float4*)&Ws[wr][wc * 4] = wv;
    __syncthreads();
#pragma unroll
    for (int kk = 0; kk < 16; ++kk) {
      const float4 a = *(const float4*)&At[kk][ty * 4];
      const float4 w = *(const float4*)&Ws[kk][tx * 4];
      c[0][0] += a.x * w.x; c[0][1] += a.x * w.y; c[0][2] += a.x * w.z; c[0][3] += a.x * w.w;
      c[1][0] += a.y * w.x; c[1][1] += a.y * w.y; c[1][2] += a.y * w.z; c[1][3] += a.y * w.w;
      c[2][0] += a.z * w.x; c[2][1] += a.z * w.y; c[2][2] += a.z * w.z; c[2][3] += a.z * w.w;
      c[3][0] += a.w * w.x; c[3][1] += a.w * w.y; c[3][2] += a.w * w.z; c[3][3] += a.w * w.w;
    }
    __syncthreads();
  }
#pragma unroll
  for (int i = 0; i < 4; ++i) {
    const int row = row0 + ty * 4 + i;
    const int col = col0 + tx * 4;
    float o0 = c[i][0], o1 = c[i][1], o2 = c[i][2], o3 = c[i][3];
    if (MODE == 1) {
      const float av = ex1[row];
      o0 += av * ex2[col + 0]; o1 += av * ex2[col + 1];
      o2 += av * ex2[col + 2]; o3 += av * ex2[col + 3];
    } else if (MODE == 2) {
      o0 += ex2[col + 0]; o1 += ex2[col + 1];
      o2 += ex2[col + 2]; o3 += ex2[col + 3];
    }
    *(float4*)&C[(size_t)row * 256 + col] = make_float4(o0, o1, o2, o3);
  }
}

// ---------------------------------------------------------------------------
// Fused 16-head attention (flash-style, fp32).
// Block: (b, tile of 32 q-rows). Thread t: head h = t&15, row-group pg = t>>4,
// owns rows pA = p0+pg, pB = p0+pg+16. k/v read from global (L3-resident),
// consecutive lanes cover consecutive heads -> coalesced 256B per quad.
// ---------------------------------------------------------------------------
__global__ __launch_bounds__(256, 2) void attn_kernel(
    const float* __restrict__ q, const float* __restrict__ kbuf,
    const float* __restrict__ vbuf, const float* __restrict__ mask,
    float* __restrict__ ao) {
  __shared__ float ms[32][36];
  const int t = threadIdx.x;
  const int h = t & 15, pg = t >> 4;
  const int b = blockIdx.y;
  const int p0 = blockIdx.x * 32;
  const int pA = p0 + pg, pB = p0 + pg + 16;

  float qr0[16], qr1[16], acc0[16], acc1[16];
#pragma unroll
  for (int d = 0; d < 16; ++d) { acc0[d] = 0.f; acc1[d] = 0.f; }
  float m0 = -INFINITY, m1 = -INFINITY, l0 = 0.f, l1 = 0.f;
  {
    const float* qp =
        &q[((size_t)b * PP + imin(pA, PP - 1)) * 256 + h * 16];
#pragma unroll
    for (int dq = 0; dq < 4; ++dq) {
      const float4 qv = *(const float4*)&qp[dq * 4];
      qr0[dq * 4 + 0] = qv.x; qr0[dq * 4 + 1] = qv.y;
      qr0[dq * 4 + 2] = qv.z; qr0[dq * 4 + 3] = qv.w;
    }
  }
  {
    const float* qp =
        &q[((size_t)b * PP + imin(pB, PP - 1)) * 256 + h * 16];
#pragma unroll
    for (int dq = 0; dq < 4; ++dq) {
      const float4 qv = *(const float4*)&qp[dq * 4];
      qr1[dq * 4 + 0] = qv.x; qr1[dq * 4 + 1] = qv.y;
      qr1[dq * 4 + 2] = qv.z; qr1[dq * 4 + 3] = qv.w;
    }
  }
  const int mp = t >> 3, mq = t & 7;

  for (int n0 = 0; n0 < NN; n0 += 32) {
    {  // stage mask tile (coalesced)
      const float* mrow =
          &mask[((size_t)b * PP + imin(p0 + mp, PP - 1)) * NN];
      const int nb = n0 + mq * 4;
      float4 mv;
      if (nb + 3 < NN) mv = *(const float4*)&mrow[nb];
      else
        mv = make_float4(mrow[imin(nb, NN - 1)], mrow[imin(nb + 1, NN - 1)],
                         mrow[imin(nb + 2, NN - 1)], mrow[imin(nb + 3, NN - 1)]);
      *(float4*)&ms[mp][mq * 4] = mv;
    }
    __syncthreads();

    float s0[32], s1[32];
#pragma unroll
    for (int n = 0; n < 32; ++n) {
      const int nn = n0 + n;
      const float* kp =
          &kbuf[((size_t)b * NN + imin(nn, NN - 1)) * 256 + h * 16];
      const float4 ka = *(const float4*)&kp[0];
      const float4 kb = *(const float4*)&kp[4];
      const float4 kc = *(const float4*)&kp[8];
      const float4 kd = *(const float4*)&kp[12];
      const float kv[16] = {ka.x, ka.y, ka.z, ka.w, kb.x, kb.y, kb.z, kb.w,
                            kc.x, kc.y, kc.z, kc.w, kd.x, kd.y, kd.z, kd.w};
      float d0 = 0.f, d1 = 0.f;
#pragma unroll
      for (int d = 0; d < 16; ++d) {
        d0 += qr0[d] * kv[d];
        d1 += qr1[d] * kv[d];
      }
      if (nn < NN) {
        s0[n] = d0 * 0.25f + ms[pg][n];
        s1[n] = d1 * 0.25f + ms[pg + 16][n];
      } else {
        s0[n] = -INFINITY;
        s1[n] = -INFINITY;
      }
    }
    float tm0 = -INFINITY, tm1 = -INFINITY;
#pragma unroll
    for (int n = 0; n < 32; ++n) {
      tm0 = fmaxf(tm0, s0[n]);
      tm1 = fmaxf(tm1, s1[n]);
    }
    const float mn0 = fmaxf(m0, tm0), mn1 = fmaxf(m1, tm1);
    const float sc0 = __expf(m0 - mn0), sc1 = __expf(m1 - mn1);
    m0 = mn0; m1 = mn1;
    float ls0 = 0.f, ls1 = 0.f;
#pragma unroll
    for (int n = 0; n < 32; ++n) {
      const float e0 = __expf(s0[n] - mn0); s0[n] = e0; ls0 += e0;
      const float e1 = __expf(s1[n] - mn1); s1[n] = e1; ls1 += e1;
    }
    l0 = l0 * sc0 + ls0;
    l1 = l1 * sc1 + ls1;
#pragma unroll
    for (int d = 0; d < 16; ++d) { acc0[d] *= sc0; acc1[d] *= sc1; }
#pragma unroll
    for (int n = 0; n < 32; ++n) {
      const float* vp =
          &vbuf[((size_t)b * NN + imin(n0 + n, NN - 1)) * 256 + h * 16];
      const float4 va = *(const float4*)&vp[0];
      const float4 vb = *(const float4*)&vp[4];
      const float4 vc = *(const float4*)&vp[8];
      const float4 vd = *(const float4*)&vp[12];
      const float vv[16] = {va.x, va.y, va.z, va.w, vb.x, vb.y, vb.z, vb.w,
                            vc.x, vc.y, vc.z, vc.w, vd.x, vd.y, vd.z, vd.w};
      const float e0 = s0[n], e1 = s1[n];
#pragma unroll
      for (int d = 0; d < 16; ++d) {
        acc0[d] += e0 * vv[d];
        acc1[d] += e1 * vv[d];
      }
    }
    __syncthreads();
  }
  if (pA < PP) {
    const float inv = 1.0f / l0;
    float* op = &ao[((size_t)b * PP + pA) * 256 + h * 16];
#pragma unroll
    for (int dq = 0; dq < 4; ++dq)
      *(float4*)&op[dq * 4] =
          make_float4(acc0[dq * 4] * inv, acc0[dq * 4 + 1] * inv,
                      acc0[dq * 4 + 2] * inv, acc0[dq * 4 + 3] * inv);
  }
  if (pB < PP) {
    const float inv = 1.0f / l1;
    float* op = &ao[((size_t)b * PP + pB) * 256 + h * 16];
#pragma unroll
    for (int dq = 0; dq < 4; ++dq)
      *(float4*)&op[dq * 4] =
          make_float4(acc1[dq * 4] * inv, acc1[dq * 4 + 1] * inv,
                      acc1[dq * 4 + 2] * inv, acc1[dq * 4 + 3] * inv);
  }
}

// ---------------------------------------------------------------------------
// score2 = mh @ nodes^T per batch, epilogue 10*tanh(x/16). NT GEMM 64x64.
// ---------------------------------------------------------------------------
__global__ __launch_bounds__(256) void score2_kernel(
    const float* __restrict__ mh, const float* __restrict__ nodes,
    float* __restrict__ s2) {
  __shared__ float At[16][68];
  __shared__ float Bt[16][68];
  const int t = threadIdx.x;
  const int tx = t & 15, ty = t >> 4;
  const int b = blockIdx.z;
  const int row0 = blockIdx.y * 64, col0 = blockIdx.x * 64;
  const float* Ab = mh + (size_t)b * PP * 256;
  const float* Bb = nodes + (size_t)b * NN * 256;
  float* Cb = s2 + (size_t)b * PP * NN;
  const int lr = t >> 2, lkq = t & 3;
  float c[4][4] = {};
  for (int kc = 0; kc < 16; ++kc) {
    const float4 av = *(const float4*)&Ab[(size_t)imin(row0 + lr, PP - 1) * 256 +
                                          kc * 16 + lkq * 4];
    const float4 bv = *(const float4*)&Bb[(size_t)imin(col0 + lr, NN - 1) * 256 +
                                          kc * 16 + lkq * 4];
    At[lkq * 4 + 0][lr] = av.x;
    At[lkq * 4 + 1][lr] = av.y;
    At[lkq * 4 + 2][lr] = av.z;
    At[lkq * 4 + 3][lr] = av.w;
    Bt[lkq * 4 + 0][lr] = bv.x;
    Bt[lkq * 4 + 1][lr] = bv.y;
    Bt[lkq * 4 + 2][lr] = bv.z;
    Bt[lkq * 4 + 3][lr] = bv.w;
    __syncthreads();
#pragma unroll
    for (int kk = 0; kk < 16; ++kk) {
      const float4 a = *(const float4*)&At[kk][ty * 4];
      const float4 w = *(const float4*)&Bt[kk][tx * 4];
      c[0][0] += a.x * w.x; c[0][1] += a.x * w.y; c[0][2] += a.x * w.z; c[0][3] += a.x * w.w;
      c[1][0] += a.y * w.x; c[1][1] += a.y * w.y; c[1][2] += a.y * w.z; c[1][3] += a.y * w.w;
      c[2][0] += a.z * w.x; c[2][1] += a.z * w.y; c[2][2] += a.z * w.z; c[2][3] += a.z * w.w;
      c[3][0] += a.w * w.x; c[3][1] += a.w * w.y; c[3][2] += a.w * w.z; c[3][3] += a.w * w.w;
    }
    __syncthreads();
  }
#pragma unroll
  for (int i = 0; i < 4; ++i) {
    const int row = row0 + ty * 4 + i;
    if (row < PP) {
      const int col = col0 + tx * 4;
      float o[4];
#pragma unroll
      for (int j = 0; j < 4; ++j) o[j] = 10.0f * tanhf(c[i][j] * 0.0625f);
      if (col + 3 < NN) {
        *(float4*)&Cb[(size_t)row * NN + col] = make_float4(o[0], o[1], o[2], o[3]);
      } else {
#pragma unroll
        for (int j = 0; j < 4; ++j)
          if (col + j < NN) Cb[(size_t)row * NN + col + j] = o[j];
      }
    }
  }
}

// ---------------------------------------------------------------------------
// Row softmax over n of (s2 + mask). One block per (b,p) row.
// ---------------------------------------------------------------------------
__global__ __launch_bounds__(256) void softmax_rows(
    const float* __restrict__ s2, const float* __restrict__ mask,
    float* __restrict__ out) {
  const int row = blockIdx.x;  // b*1000 + p
  const size_t base = (size_t)row * NN;
  const int t = threadIdx.x;
  __shared__ float wm[4], wl[4];
  const bool act = t < 250;
  float v0 = 0.f, v1 = 0.f, v2 = 0.f, v3 = 0.f;
  float m = -3.0e38f, l = 0.f;  // finite init: avoids -inf - -inf NaN in reduce
  if (act) {
    const float4 a = *(const float4*)&s2[base + 4 * t];
    const float4 bq = *(const float4*)&mask[base + 4 * t];
    v0 = a.x + bq.x; v1 = a.y + bq.y; v2 = a.z + bq.z; v3 = a.w + bq.w;
    m = fmaxf(fmaxf(v0, v1), fmaxf(v2, v3));
    l = __expf(v0 - m) + __expf(v1 - m) + __expf(v2 - m) + __expf(v3 - m);
  }
#pragma unroll
  for (int off = 1; off < 64; off <<= 1) {
    const float om = __shfl_xor(m, off, 64);
    const float ol = __shfl_xor(l, off, 64);
    const float nm = fmaxf(m, om);
    l = l * __expf(m - nm) + ol * __expf(om - nm);
    m = nm;
  }
  if ((t & 63) == 0) { wm[t >> 6] = m; wl[t >> 6] = l; }
  __syncthreads();
  float fm = wm[0], fl = wl[0];
#pragma unroll
  for (int w = 1; w < 4; ++w) {
    const float om = wm[w], ol = wl[w];
    const float nm = fmaxf(fm, om);
    fl = fl * __expf(fm - nm) + ol * __expf(om - nm);
    fm = nm;
  }
  if (act) {
    const float inv = 1.0f / fl;
    *(float4*)&out[base + 4 * t] =
        make_float4(__expf(v0 - fm) * inv, __expf(v1 - fm) * inv,
                    __expf(v2 - fm) * inv, __expf(v3 - fm) * inv);
  }
}

// ---------------------------------------------------------------------------
extern "C" void kernel_launch(void* const* d_in, const int* in_sizes, int n_in,
                              void* d_out, int out_size, void* d_ws,
                              size_t ws_size, hipStream_t stream) {
  const float* last  = (const float*)d_in[0];   // [16,1000,256]
  const float* attr  = (const float*)d_in[1];   // [16,1000,1]
  const float* mask  = (const float*)d_in[2];   // [16,1000,1000]
  const float* nodes = (const float*)d_in[3];   // [16,1000,256]
  const float* Wq    = (const float*)d_in[4];   // [257,256]
  const float* Wk    = (const float*)d_in[5];   // [256,256]
  const float* Wv    = (const float*)d_in[6];   // [256,256]
  const float* Wc    = (const float*)d_in[7];   // [256,256]
  const float* bc    = (const float*)d_in[8];   // [256]
  float* out = (float*)d_out;

  float* ws  = (float*)d_ws;
  float* qb  = ws;                  //  4,096,000
  float* kb  = ws + 4096000;        //  4,096,000
  float* vb  = ws + 8192000;        //  4,096,000
  float* aob = ws + 12288000;       //  4,096,000
  float* mhb = ws + 16384000;       //  4,096,000
  float* s2b = ws + 20480000;       // 16,000,000  (total 145.9 MB)

  const dim3 blk(256);
  const dim3 gg(4, 250);
  gemm256_kernel<0><<<gg, blk, 0, stream>>>(nodes, Wk, kb, nullptr, nullptr);
  gemm256_kernel<0><<<gg, blk, 0, stream>>>(nodes, Wv, vb, nullptr, nullptr);
  gemm256_kernel<1><<<gg, blk, 0, stream>>>(last, Wq, qb, attr, Wq + 256 * 256);
  attn_kernel<<<dim3(32, 16), blk, 0, stream>>>(qb, kb, vb, mask, aob);
  gemm256_kernel<2><<<gg, blk, 0, stream>>>(aob, Wc, mhb, nullptr, bc);
  score2_kernel<<<dim3(16, 16, 16), blk, 0, stream>>>(mhb, nodes, s2b);
  softmax_rows<<<dim3(16000), blk, 0, stream>>>(s2b, mask, out);
}

// Round 3
// 958.579 us; speedup vs baseline: 2.2569x; 2.2569x over previous
//
#include <hip/hip_runtime.h>
#include <math.h>

#define BB 16
#define PP 1000
#define NN 1000

typedef short bf16x8 __attribute__((ext_vector_type(8)));
typedef float f32x4 __attribute__((ext_vector_type(4)));

static __device__ __forceinline__ int imin(int a, int b) { return a < b ? a : b; }

static __device__ __forceinline__ ushort f2bf(float f) {
  unsigned u = __builtin_bit_cast(unsigned, f);
  u = (u + 0x7FFFu + ((u >> 16) & 1u)) >> 16;
  return (ushort)u;
}
static __device__ __forceinline__ float bf2f(ushort h) {
  unsigned u = ((unsigned)h) << 16;
  return __builtin_bit_cast(float, u);
}

// ---------------------------------------------------------------------------
// GEMM: C[M x 256] = A[M x 256] @ W[256 x 256]  (M = 16000 = 16 b x 1000 rows)
// MODE 0: f32 out                      (V)
// MODE 1: += attr[row]*Wq_row256[col], bf16 out padded [b][1024][256]   (Q)
// MODE 2: += bias[col], f32 out        (Wc)
// MODE 3: bf16 out padded              (K)
// ---------------------------------------------------------------------------
template <int MODE>
__global__ __launch_bounds__(256) void gemm256_kernel(
    const float* __restrict__ A, const float* __restrict__ W,
    float* __restrict__ C, ushort* __restrict__ Cb,
    const float* __restrict__ ex1, const float* __restrict__ ex2) {
  __shared__ float At[16][68];
  __shared__ float Ws[16][68];
  const int t = threadIdx.x;
  const int tx = t & 15, ty = t >> 4;
  const int row0 = blockIdx.y * 64, col0 = blockIdx.x * 64;
  const int ar = t >> 2, akq = t & 3;
  const int wr = t >> 4, wc = t & 15;
  float c[4][4] = {};
  for (int kc = 0; kc < 16; ++kc) {
    const float4 av =
        *(const float4*)&A[(size_t)(row0 + ar) * 256 + kc * 16 + akq * 4];
    const float4 wv =
        *(const float4*)&W[(size_t)(kc * 16 + wr) * 256 + col0 + wc * 4];
    At[akq * 4 + 0][ar] = av.x;
    At[akq * 4 + 1][ar] = av.y;
    At[akq * 4 + 2][ar] = av.z;
    At[akq * 4 + 3][ar] = av.w;
    *(float4*)&Ws[wr][wc * 4] = wv;
    __syncthreads();
#pragma unroll
    for (int kk = 0; kk < 16; ++kk) {
      const float4 a = *(const float4*)&At[kk][ty * 4];
      const float4 w = *(const float4*)&Ws[kk][tx * 4];
      c[0][0] += a.x * w.x; c[0][1] += a.x * w.y; c[0][2] += a.x * w.z; c[0][3] += a.x * w.w;
      c[1][0] += a.y * w.x; c[1][1] += a.y * w.y; c[1][2] += a.y * w.z; c[1][3] += a.y * w.w;
      c[2][0] += a.z * w.x; c[2][1] += a.z * w.y; c[2][2] += a.z * w.z; c[2][3] += a.z * w.w;
      c[3][0] += a.w * w.x; c[3][1] += a.w * w.y; c[3][2] += a.w * w.z; c[3][3] += a.w * w.w;
    }
    __syncthreads();
  }
#pragma unroll
  for (int i = 0; i < 4; ++i) {
    const int row = row0 + ty * 4 + i;
    const int col = col0 + tx * 4;
    float o0 = c[i][0], o1 = c[i][1], o2 = c[i][2], o3 = c[i][3];
    if (MODE == 1) {
      const float av = ex1[row];
      o0 += av * ex2[col + 0]; o1 += av * ex2[col + 1];
      o2 += av * ex2[col + 2]; o3 += av * ex2[col + 3];
    } else if (MODE == 2) {
      o0 += ex2[col + 0]; o1 += ex2[col + 1];
      o2 += ex2[col + 2]; o3 += ex2[col + 3];
    }
    if (MODE == 0 || MODE == 2) {
      *(float4*)&C[(size_t)row * 256 + col] = make_float4(o0, o1, o2, o3);
    } else {
      const int b = row / 1000;
      const int p = row - b * 1000;
      ushort4 o;
      o.x = f2bf(o0); o.y = f2bf(o1); o.z = f2bf(o2); o.w = f2bf(o3);
      *(ushort4*)&Cb[((size_t)(b * 1024 + p)) * 256 + col] = o;
    }
  }
}

// ---------------------------------------------------------------------------
// V transpose: vb f32 [b][1000][256] -> vt bf16 [b*16+h][16 d][1024 n]
// ---------------------------------------------------------------------------
__global__ __launch_bounds__(256) void vtrans_kernel(
    const float* __restrict__ vb, ushort* __restrict__ vt) {
  __shared__ float T[64][65];
  const int t = threadIdx.x;
  const int b = blockIdx.z;
  const int n0 = blockIdx.x * 64;
  const int c0 = blockIdx.y * 64;
  {
    const int lr = t >> 4;
    const int lc = (t & 15) * 4;
#pragma unroll
    for (int i = 0; i < 4; ++i) {
      const int n_l = lr + i * 16;
      const int row = imin(n0 + n_l, PP - 1);
      const float4 v =
          *(const float4*)&vb[((size_t)b * PP + row) * 256 + c0 + lc];
      T[n_l][lc + 0] = v.x;
      T[n_l][lc + 1] = v.y;
      T[n_l][lc + 2] = v.z;
      T[n_l][lc + 3] = v.w;
    }
  }
  __syncthreads();
  {
    const int n_l = (t & 15) * 4;
#pragma unroll
    for (int i = 0; i < 4; ++i) {
      const int c_l = (t >> 4) + i * 16;
      const int hd = c0 + c_l;
      ushort4 o;
      o.x = f2bf(T[n_l + 0][c_l]);
      o.y = f2bf(T[n_l + 1][c_l]);
      o.z = f2bf(T[n_l + 2][c_l]);
      o.w = f2bf(T[n_l + 3][c_l]);
      *(ushort4*)&vt[((size_t)(b * 16 + (hd >> 4)) * 16 + (hd & 15)) * 1024 +
                     n0 + n_l] = o;
    }
  }
}

// ---------------------------------------------------------------------------
// MFMA attention. 1 wave/block. block = (p-tile 16, head h, batch b).
// Phase1: S = QK^T/4 + mask via 63 mfma_16x16x32 (d padded 16->32),
//         running row-max in regs, S->LDS bf16 (XOR-swizzled [16][1024]).
// Phase2: probs = exp(S - rowmax) in-place, row sums.
// Phase3: out = probs @ V via 32 mfma (Vt layout), scale 1/sum at store.
// ---------------------------------------------------------------------------
__global__ __launch_bounds__(64) void attn_mfma_kernel(
    const ushort* __restrict__ qb, const ushort* __restrict__ kb,
    const ushort* __restrict__ vt, const float* __restrict__ mask,
    float* __restrict__ ao) {
  __shared__ ushort Sl[16 * 1024];
  __shared__ float rm[16];
  __shared__ float sums[16];

  const int l = threadIdx.x;       // 0..63
  const int lo = l & 15;
  const int g = l >> 4;            // lane group 0..3
  const int pt = blockIdx.x;       // 0..62
  const int h = blockIdx.y;
  const int b = blockIdx.z;
  const int p0 = pt * 16;

  // swizzled element offset: bank-spread rows (T2-style XOR)
  auto elem = [&](int p, int n) { return (p << 10) + (n ^ ((p & 7) << 3)); };

  // phase 0: poison-proof the pad columns n=1008..1023
  {
    const ushort negbf = f2bf(-1e30f);
    const int p = l >> 2;
    const int nb = 1008 + (l & 3) * 4;
#pragma unroll
    for (int k = 0; k < 4; ++k) Sl[elem(p, nb + k)] = negbf;
  }

  // Q fragment (constant across n): A[row=lo][k=8g+j], k>=16 -> 0
  bf16x8 qf = {};
  if (g < 2)
    qf = *(const bf16x8*)&qb[((size_t)(b * 1024 + p0 + lo)) * 256 + h * 16 +
                             8 * g];

  float maxacc[4] = {-INFINITY, -INFINITY, -INFINITY, -INFINITY};

  // prefetch tile 0
  bf16x8 kf_next = {};
  if (g < 2)
    kf_next = *(const bf16x8*)&kb[((size_t)(b * 1024 + 0 + lo)) * 256 +
                                  h * 16 + 8 * g];
  float mv_next[4];
#pragma unroll
  for (int r = 0; r < 4; ++r) {
    const int pm = imin(p0 + 4 * g + r, PP - 1);
    mv_next[r] = mask[((size_t)b * PP + pm) * NN + imin(lo, NN - 1)];
  }

  for (int nt = 0; nt < 63; ++nt) {
    const bf16x8 kf = kf_next;
    float mv[4];
#pragma unroll
    for (int r = 0; r < 4; ++r) mv[r] = mv_next[r];
    if (nt < 62) {
      const int n1 = (nt + 1) * 16 + lo;
      if (g < 2)
        kf_next = *(const bf16x8*)&kb[((size_t)(b * 1024 + n1)) * 256 +
                                      h * 16 + 8 * g];
#pragma unroll
      for (int r = 0; r < 4; ++r) {
        const int pm = imin(p0 + 4 * g + r, PP - 1);
        mv_next[r] = mask[((size_t)b * PP + pm) * NN + imin(n1, NN - 1)];
      }
    }
    f32x4 cc = {0.f, 0.f, 0.f, 0.f};
    cc = __builtin_amdgcn_mfma_f32_16x16x32_bf16(qf, kf, cc, 0, 0, 0);
    const int n = nt * 16 + lo;  // this lane's column
#pragma unroll
    for (int r = 0; r < 4; ++r) {
      float s = cc[r] * 0.25f + mv[r];
      if (n >= NN) s = -1e30f;
      maxacc[r] = fmaxf(maxacc[r], s);
      Sl[elem(4 * g + r, n)] = f2bf(s);
    }
  }

  // row-max reduce across the 16 column-lanes; lane lo==0 publishes
#pragma unroll
  for (int r = 0; r < 4; ++r) {
#pragma unroll
    for (int off = 1; off < 16; off <<= 1)
      maxacc[r] = fmaxf(maxacc[r], __shfl_xor(maxacc[r], off, 64));
  }
  if (lo == 0) {
#pragma unroll
    for (int r = 0; r < 4; ++r) rm[4 * g + r] = maxacc[r];
  }
  __syncthreads();

  // phase 2: exp + sum, write probs back (unnormalized)
  {
    const float mr = rm[lo];
    float lsum = 0.f;
    for (int cc2 = 0; cc2 < 32; ++cc2) {
      ushort* pp = &Sl[elem(lo, cc2 * 32 + g * 8)];
      bf16x8 v = *(bf16x8*)pp;
      bf16x8 o;
#pragma unroll
      for (int j = 0; j < 8; ++j) {
        const float e = __expf(bf2f((ushort)v[j]) - mr);
        lsum += e;
        o[j] = (short)f2bf(e);
      }
      *(bf16x8*)pp = o;
    }
    lsum += __shfl_xor(lsum, 16, 64);
    lsum += __shfl_xor(lsum, 32, 64);
    if (g == 0) sums[lo] = lsum;
  }
  __syncthreads();

  // phase 3: PV. A[row=lo][k=n], B = Vt[d=lo][n]
  f32x4 acc = {0.f, 0.f, 0.f, 0.f};
  const ushort* vrow = &vt[((size_t)(b * 16 + h) * 16 + lo) * 1024];
  bf16x8 vf_next = *(const bf16x8*)&vrow[8 * g];
  for (int c3 = 0; c3 < 32; ++c3) {
    const bf16x8 vf = vf_next;
    if (c3 < 31) vf_next = *(const bf16x8*)&vrow[(c3 + 1) * 32 + 8 * g];
    const bf16x8 pf = *(const bf16x8*)&Sl[elem(lo, c3 * 32 + g * 8)];
    acc = __builtin_amdgcn_mfma_f32_16x16x32_bf16(pf, vf, acc, 0, 0, 0);
  }
#pragma unroll
  for (int r = 0; r < 4; ++r) {
    const int p = p0 + 4 * g + r;
    if (p < PP) {
      const float inv = 1.0f / sums[4 * g + r];
      ao[((size_t)b * PP + p) * 256 + h * 16 + lo] = acc[r] * inv;
    }
  }
}

// ---------------------------------------------------------------------------
// score2 = mh @ nodes^T per batch, epilogue 10*tanh(x/16). NT GEMM 64x64.
// ---------------------------------------------------------------------------
__global__ __launch_bounds__(256) void score2_kernel(
    const float* __restrict__ mh, const float* __restrict__ nodes,
    float* __restrict__ s2) {
  __shared__ float At[16][68];
  __shared__ float Bt[16][68];
  const int t = threadIdx.x;
  const int tx = t & 15, ty = t >> 4;
  const int b = blockIdx.z;
  const int row0 = blockIdx.y * 64, col0 = blockIdx.x * 64;
  const float* Ab = mh + (size_t)b * PP * 256;
  const float* Bb = nodes + (size_t)b * NN * 256;
  float* Cb = s2 + (size_t)b * PP * NN;
  const int lr = t >> 2, lkq = t & 3;
  float c[4][4] = {};
  for (int kc = 0; kc < 16; ++kc) {
    const float4 av = *(const float4*)&Ab[(size_t)imin(row0 + lr, PP - 1) * 256 +
                                          kc * 16 + lkq * 4];
    const float4 bv = *(const float4*)&Bb[(size_t)imin(col0 + lr, NN - 1) * 256 +
                                          kc * 16 + lkq * 4];
    At[lkq * 4 + 0][lr] = av.x;
    At[lkq * 4 + 1][lr] = av.y;
    At[lkq * 4 + 2][lr] = av.z;
    At[lkq * 4 + 3][lr] = av.w;
    Bt[lkq * 4 + 0][lr] = bv.x;
    Bt[lkq * 4 + 1][lr] = bv.y;
    Bt[lkq * 4 + 2][lr] = bv.z;
    Bt[lkq * 4 + 3][lr] = bv.w;
    __syncthreads();
#pragma unroll
    for (int kk = 0; kk < 16; ++kk) {
      const float4 a = *(const float4*)&At[kk][ty * 4];
      const float4 w = *(const float4*)&Bt[kk][tx * 4];
      c[0][0] += a.x * w.x; c[0][1] += a.x * w.y; c[0][2] += a.x * w.z; c[0][3] += a.x * w.w;
      c[1][0] += a.y * w.x; c[1][1] += a.y * w.y; c[1][2] += a.y * w.z; c[1][3] += a.y * w.w;
      c[2][0] += a.z * w.x; c[2][1] += a.z * w.y; c[2][2] += a.z * w.z; c[2][3] += a.z * w.w;
      c[3][0] += a.w * w.x; c[3][1] += a.w * w.y; c[3][2] += a.w * w.z; c[3][3] += a.w * w.w;
    }
    __syncthreads();
  }
#pragma unroll
  for (int i = 0; i < 4; ++i) {
    const int row = row0 + ty * 4 + i;
    if (row < PP) {
      const int col = col0 + tx * 4;
      float o[4];
#pragma unroll
      for (int j = 0; j < 4; ++j) o[j] = 10.0f * tanhf(c[i][j] * 0.0625f);
      if (col + 3 < NN) {
        *(float4*)&Cb[(size_t)row * NN + col] = make_float4(o[0], o[1], o[2], o[3]);
      } else {
#pragma unroll
        for (int j = 0; j < 4; ++j)
          if (col + j < NN) Cb[(size_t)row * NN + col + j] = o[j];
      }
    }
  }
}

// ---------------------------------------------------------------------------
// Row softmax over n of (s2 + mask). One block per (b,p) row.
// ---------------------------------------------------------------------------
__global__ __launch_bounds__(256) void softmax_rows(
    const float* __restrict__ s2, const float* __restrict__ mask,
    float* __restrict__ out) {
  const int row = blockIdx.x;
  const size_t base = (size_t)row * NN;
  const int t = threadIdx.x;
  __shared__ float wm[4], wl[4];
  const bool act = t < 250;
  float v0 = 0.f, v1 = 0.f, v2 = 0.f, v3 = 0.f;
  float m = -3.0e38f, l = 0.f;
  if (act) {
    const float4 a = *(const float4*)&s2[base + 4 * t];
    const float4 bq = *(const float4*)&mask[base + 4 * t];
    v0 = a.x + bq.x; v1 = a.y + bq.y; v2 = a.z + bq.z; v3 = a.w + bq.w;
    m = fmaxf(fmaxf(v0, v1), fmaxf(v2, v3));
    l = __expf(v0 - m) + __expf(v1 - m) + __expf(v2 - m) + __expf(v3 - m);
  }
#pragma unroll
  for (int off = 1; off < 64; off <<= 1) {
    const float om = __shfl_xor(m, off, 64);
    const float ol = __shfl_xor(l, off, 64);
    const float nm = fmaxf(m, om);
    l = l * __expf(m - nm) + ol * __expf(om - nm);
    m = nm;
  }
  if ((t & 63) == 0) { wm[t >> 6] = m; wl[t >> 6] = l; }
  __syncthreads();
  float fm = wm[0], fl = wl[0];
#pragma unroll
  for (int w = 1; w < 4; ++w) {
    const float om = wm[w], ol = wl[w];
    const float nm = fmaxf(fm, om);
    fl = fl * __expf(fm - nm) + ol * __expf(om - nm);
    fm = nm;
  }
  if (act) {
    const float inv = 1.0f / fl;
    *(float4*)&out[base + 4 * t] =
        make_float4(__expf(v0 - fm) * inv, __expf(v1 - fm) * inv,
                    __expf(v2 - fm) * inv, __expf(v3 - fm) * inv);
  }
}

// ---------------------------------------------------------------------------
extern "C" void kernel_launch(void* const* d_in, const int* in_sizes, int n_in,
                              void* d_out, int out_size, void* d_ws,
                              size_t ws_size, hipStream_t stream) {
  const float* last  = (const float*)d_in[0];
  const float* attr  = (const float*)d_in[1];
  const float* mask  = (const float*)d_in[2];
  const float* nodes = (const float*)d_in[3];
  const float* Wq    = (const float*)d_in[4];
  const float* Wk    = (const float*)d_in[5];
  const float* Wv    = (const float*)d_in[6];
  const float* Wc    = (const float*)d_in[7];
  const float* bc    = (const float*)d_in[8];
  float* out = (float*)d_out;

  char* base = (char*)d_ws;
  ushort* qbb = (ushort*)(base);                    //  8,388,608 B
  ushort* kbb = (ushort*)(base + 8388608);          //  8,388,608 B
  ushort* vtb = (ushort*)(base + 16777216);         //  8,388,608 B
  float*  vb  = (float*)(base + 25165824);          // 16,384,000 B
  float*  aob = (float*)(base + 41549824);          // 16,384,000 B
  float*  mhb = (float*)(base + 57933824);          // 16,384,000 B
  float*  s2b = (float*)(base + 74317824);          // 64,000,000 B -> 138.3 MB

  const dim3 blk(256);
  const dim3 gg(4, 250);
  gemm256_kernel<3><<<gg, blk, 0, stream>>>(nodes, Wk, nullptr, kbb, nullptr, nullptr);
  gemm256_kernel<0><<<gg, blk, 0, stream>>>(nodes, Wv, vb, nullptr, nullptr, nullptr);
  gemm256_kernel<1><<<gg, blk, 0, stream>>>(last, Wq, nullptr, qbb, attr, Wq + 256 * 256);
  vtrans_kernel<<<dim3(16, 4, 16), blk, 0, stream>>>(vb, vtb);
  attn_mfma_kernel<<<dim3(63, 16, 16), dim3(64), 0, stream>>>(qbb, kbb, vtb, mask, aob);
  gemm256_kernel<2><<<gg, blk, 0, stream>>>(aob, Wc, mhb, nullptr, nullptr, bc);
  score2_kernel<<<dim3(16, 16, 16), blk, 0, stream>>>(mhb, nodes, s2b);
  softmax_rows<<<dim3(16000), blk, 0, stream>>>(s2b, mask, out);
}

// Round 4
// 520.939 us; speedup vs baseline: 4.1529x; 1.8401x over previous
//
#include <hip/hip_runtime.h>
#include <math.h>

#define BB 16
#define PP 1000
#define NN 1000

typedef short bf16x8 __attribute__((ext_vector_type(8)));
typedef float f32x4 __attribute__((ext_vector_type(4)));
typedef float f32x16 __attribute__((ext_vector_type(16)));
typedef unsigned u32x4 __attribute__((ext_vector_type(4)));

static __device__ __forceinline__ int imin(int a, int b) { return a < b ? a : b; }

static __device__ __forceinline__ ushort f2bf(float f) {
  unsigned u = __builtin_bit_cast(unsigned, f);
  u = (u + 0x7FFFu + ((u >> 16) & 1u)) >> 16;
  return (ushort)u;
}
static __device__ __forceinline__ float bf2f(ushort h) {
  unsigned u = ((unsigned)h) << 16;
  return __builtin_bit_cast(float, u);
}
static __device__ __forceinline__ unsigned cvt_pk_bf16(float lo, float hi) {
  unsigned r;
  asm("v_cvt_pk_bf16_f32 %0, %1, %2" : "=v"(r) : "v"(lo), "v"(hi));
  return r;
}

// ---------------------------------------------------------------------------
// GEMM: C[M x 256] = A[M x 256] @ W[256 x 256]  (M = 16000 = 16 b x 1000 rows)
// MODE 0: f32 out (V)   MODE 1: q rank-1, bf16 padded   MODE 2: +bias f32
// MODE 3: bf16 padded (K)
// ---------------------------------------------------------------------------
template <int MODE>
__global__ __launch_bounds__(256) void gemm256_kernel(
    const float* __restrict__ A, const float* __restrict__ W,
    float* __restrict__ C, ushort* __restrict__ Cb,
    const float* __restrict__ ex1, const float* __restrict__ ex2) {
  __shared__ float At[16][68];
  __shared__ float Ws[16][68];
  const int t = threadIdx.x;
  const int tx = t & 15, ty = t >> 4;
  const int row0 = blockIdx.y * 64, col0 = blockIdx.x * 64;
  const int ar = t >> 2, akq = t & 3;
  const int wr = t >> 4, wc = t & 15;
  float c[4][4] = {};
  for (int kc = 0; kc < 16; ++kc) {
    const float4 av =
        *(const float4*)&A[(size_t)(row0 + ar) * 256 + kc * 16 + akq * 4];
    const float4 wv =
        *(const float4*)&W[(size_t)(kc * 16 + wr) * 256 + col0 + wc * 4];
    At[akq * 4 + 0][ar] = av.x;
    At[akq * 4 + 1][ar] = av.y;
    At[akq * 4 + 2][ar] = av.z;
    At[akq * 4 + 3][ar] = av.w;
    *(float4*)&Ws[wr][wc * 4] = wv;
    __syncthreads();
#pragma unroll
    for (int kk = 0; kk < 16; ++kk) {
      const float4 a = *(const float4*)&At[kk][ty * 4];
      const float4 w = *(const float4*)&Ws[kk][tx * 4];
      c[0][0] += a.x * w.x; c[0][1] += a.x * w.y; c[0][2] += a.x * w.z; c[0][3] += a.x * w.w;
      c[1][0] += a.y * w.x; c[1][1] += a.y * w.y; c[1][2] += a.y * w.z; c[1][3] += a.y * w.w;
      c[2][0] += a.z * w.x; c[2][1] += a.z * w.y; c[2][2] += a.z * w.z; c[2][3] += a.z * w.w;
      c[3][0] += a.w * w.x; c[3][1] += a.w * w.y; c[3][2] += a.w * w.z; c[3][3] += a.w * w.w;
    }
    __syncthreads();
  }
#pragma unroll
  for (int i = 0; i < 4; ++i) {
    const int row = row0 + ty * 4 + i;
    const int col = col0 + tx * 4;
    float o0 = c[i][0], o1 = c[i][1], o2 = c[i][2], o3 = c[i][3];
    if (MODE == 1) {
      const float av = ex1[row];
      o0 += av * ex2[col + 0]; o1 += av * ex2[col + 1];
      o2 += av * ex2[col + 2]; o3 += av * ex2[col + 3];
    } else if (MODE == 2) {
      o0 += ex2[col + 0]; o1 += ex2[col + 1];
      o2 += ex2[col + 2]; o3 += ex2[col + 3];
    }
    if (MODE == 0 || MODE == 2) {
      *(float4*)&C[(size_t)row * 256 + col] = make_float4(o0, o1, o2, o3);
    } else {
      const int b = row / 1000;
      const int p = row - b * 1000;
      ushort4 o;
      o.x = f2bf(o0); o.y = f2bf(o1); o.z = f2bf(o2); o.w = f2bf(o3);
      *(ushort4*)&Cb[((size_t)(b * 1024 + p)) * 256 + col] = o;
    }
  }
}

// ---------------------------------------------------------------------------
// V transpose: vb f32 [b][1000][256] -> vt bf16 [b*16+h][16 d][1024 n]
// ---------------------------------------------------------------------------
__global__ __launch_bounds__(256) void vtrans_kernel(
    const float* __restrict__ vb, ushort* __restrict__ vt) {
  __shared__ float T[64][65];
  const int t = threadIdx.x;
  const int b = blockIdx.z;
  const int n0 = blockIdx.x * 64;
  const int c0 = blockIdx.y * 64;
  {
    const int lr = t >> 4;
    const int lc = (t & 15) * 4;
#pragma unroll
    for (int i = 0; i < 4; ++i) {
      const int n_l = lr + i * 16;
      const int row = imin(n0 + n_l, PP - 1);
      const float4 v =
          *(const float4*)&vb[((size_t)b * PP + row) * 256 + c0 + lc];
      T[n_l][lc + 0] = v.x;
      T[n_l][lc + 1] = v.y;
      T[n_l][lc + 2] = v.z;
      T[n_l][lc + 3] = v.w;
    }
  }
  __syncthreads();
  {
    const int n_l = (t & 15) * 4;
#pragma unroll
    for (int i = 0; i < 4; ++i) {
      const int c_l = (t >> 4) + i * 16;
      const int hd = c0 + c_l;
      ushort4 o;
      o.x = f2bf(T[n_l + 0][c_l]);
      o.y = f2bf(T[n_l + 1][c_l]);
      o.z = f2bf(T[n_l + 2][c_l]);
      o.w = f2bf(T[n_l + 3][c_l]);
      *(ushort4*)&vt[((size_t)(b * 16 + (hd >> 4)) * 16 + (hd & 15)) * 1024 +
                     n0 + n_l] = o;
    }
  }
}

// ---------------------------------------------------------------------------
// Swapped-QK^T MFMA attention. No LDS, no barriers.
// Block = 512 thr (8 waves), grid (32 ptiles, 16 b). Wave w: heads 2w, 2w+1.
// Per n-chunk 32: S^T[n][p] = mfma_32x32x16(K,Q); p = lane&31 -> softmax is
// lane-local (1 shfl_xor(32) per reduce). P->bf16 via cvt_pk + half-exchange,
// PV = 2x mfma_32x32x16(P, V^T). Defer-max THR=8.
// ---------------------------------------------------------------------------
__global__ __launch_bounds__(512) void attn_mfma2(
    const ushort* __restrict__ qb, const ushort* __restrict__ kb,
    const ushort* __restrict__ vt, const float* __restrict__ mask,
    float* __restrict__ ao) {
  const int t = threadIdx.x;
  const int l = t & 63;
  const int w = t >> 6;      // wave 0..7
  const int lp = l & 31;     // p-col (QK out) / n-row (K frag) lane index
  const int half = l >> 5;
  const int b = blockIdx.y;
  const int p0 = blockIdx.x * 32;
  const int h0 = w * 2;

  const int pm = imin(p0 + lp, PP - 1);
  const float* mrow = &mask[((size_t)b * PP + pm) * NN];

  bf16x8 qf[2];
#pragma unroll
  for (int hh = 0; hh < 2; ++hh)
    qf[hh] = *(const bf16x8*)&qb[((size_t)(b * 1024 + p0 + lp)) * 256 +
                                 (h0 + hh) * 16 + half * 8];

  f32x16 acc[2];
  float m_[2] = {-1e30f, -1e30f};
  float l_[2] = {0.f, 0.f};
#pragma unroll
  for (int hh = 0; hh < 2; ++hh)
#pragma unroll
    for (int j = 0; j < 16; ++j) acc[hh][j] = 0.f;

  for (int nt = 0; nt < 32; ++nt) {
    const int n0 = nt * 32;
    // mask values, register layout matching C/D rows: reg j <-> n = (j&3)+8*(j>>2)+4*half
    float mqa[16];
    if (nt < 31) {
#pragma unroll
      for (int q = 0; q < 4; ++q) {
        const float4 v = *(const float4*)&mrow[n0 + q * 8 + half * 4];
        mqa[q * 4 + 0] = v.x; mqa[q * 4 + 1] = v.y;
        mqa[q * 4 + 2] = v.z; mqa[q * 4 + 3] = v.w;
      }
    } else {
#pragma unroll
      for (int j = 0; j < 16; ++j) {
        const int nj = n0 + (j & 3) + 8 * (j >> 2) + half * 4;
        mqa[j] = mrow[imin(nj, NN - 1)];
      }
    }
#pragma unroll
    for (int hh = 0; hh < 2; ++hh) {
      const int h = h0 + hh;
      const bf16x8 kf =
          *(const bf16x8*)&kb[((size_t)(b * 1024 + n0 + lp)) * 256 + h * 16 +
                              half * 8];
      f32x16 cc;
#pragma unroll
      for (int j = 0; j < 16; ++j) cc[j] = 0.f;
      cc = __builtin_amdgcn_mfma_f32_32x32x16_bf16(kf, qf[hh], cc, 0, 0, 0);
      float s[16];
#pragma unroll
      for (int j = 0; j < 16; ++j) s[j] = fmaf(cc[j], 0.25f, mqa[j]);
      if (nt == 31) {
#pragma unroll
        for (int j = 0; j < 16; ++j) {
          const int nj = n0 + (j & 3) + 8 * (j >> 2) + half * 4;
          if (nj >= NN) s[j] = -1e30f;
        }
      }
      // chunk max (lane-local + cross-half)
      float pmax = s[0];
#pragma unroll
      for (int j = 1; j < 16; ++j) pmax = fmaxf(pmax, s[j]);
      pmax = fmaxf(pmax, __shfl_xor(pmax, 32, 64));
      // defer-max: rescale only when the running base is stale by >8
      if (!__all(pmax <= m_[hh] + 8.0f)) {
        const float mnew = fmaxf(m_[hh], pmax);
        const float f = __expf(m_[hh] - mnew);
        m_[hh] = mnew;
        l_[hh] *= f;
#pragma unroll
        for (int j = 0; j < 16; ++j) {
          const int pj = (j & 3) + 8 * (j >> 2) + half * 4;
          const float fj = __shfl(f, pj, 64);
          acc[hh][j] *= fj;
        }
      }
      // exp + sum
      float e[16];
      float ls = 0.f;
#pragma unroll
      for (int j = 0; j < 16; ++j) {
        e[j] = __expf(s[j] - m_[hh]);
        ls += e[j];
      }
      ls += __shfl_xor(ls, 32, 64);
      l_[hh] += ls;
      // pack P to bf16 A-frags (k = n_local). Half-exchange via shfl_xor(32).
      unsigned pk0 = cvt_pk_bf16(e[0], e[1]),  pk1 = cvt_pk_bf16(e[2], e[3]);
      unsigned pk2 = cvt_pk_bf16(e[4], e[5]),  pk3 = cvt_pk_bf16(e[6], e[7]);
      unsigned pk4 = cvt_pk_bf16(e[8], e[9]),  pk5 = cvt_pk_bf16(e[10], e[11]);
      unsigned pk6 = cvt_pk_bf16(e[12], e[13]), pk7 = cvt_pk_bf16(e[14], e[15]);
      const unsigned s0 = (unsigned)__shfl_xor((int)pk0, 32, 64);
      const unsigned s2 = (unsigned)__shfl_xor((int)pk2, 32, 64);
      const unsigned s1 = (unsigned)__shfl_xor((int)pk1, 32, 64);
      const unsigned s3 = (unsigned)__shfl_xor((int)pk3, 32, 64);
      const unsigned s4 = (unsigned)__shfl_xor((int)pk4, 32, 64);
      const unsigned s6 = (unsigned)__shfl_xor((int)pk6, 32, 64);
      const unsigned s5 = (unsigned)__shfl_xor((int)pk5, 32, 64);
      const unsigned s7 = (unsigned)__shfl_xor((int)pk7, 32, 64);
      u32x4 w1, w2;
      w1[0] = half ? s2 : pk0;  // k 0,1   | 8,9
      w1[1] = half ? s3 : pk1;  // k 2,3   | 10,11
      w1[2] = half ? pk2 : s0;  // k 4,5   | 12,13
      w1[3] = half ? pk3 : s1;  // k 6,7   | 14,15
      w2[0] = half ? s6 : pk4;  // k 16,17 | 24,25
      w2[1] = half ? s7 : pk5;  // k 18,19 | 26,27
      w2[2] = half ? pk6 : s4;  // k 20,21 | 28,29
      w2[3] = half ? pk7 : s5;  // k 22,23 | 30,31
      const bf16x8 pf1 = __builtin_bit_cast(bf16x8, w1);
      const bf16x8 pf2 = __builtin_bit_cast(bf16x8, w2);
      const ushort* vrow =
          &vt[((size_t)((b * 16 + h) * 16 + (lp & 15))) * 1024];
      const bf16x8 vf1 = *(const bf16x8*)&vrow[n0 + half * 8];
      const bf16x8 vf2 = *(const bf16x8*)&vrow[n0 + 16 + half * 8];
      acc[hh] = __builtin_amdgcn_mfma_f32_32x32x16_bf16(pf1, vf1, acc[hh], 0, 0, 0);
      acc[hh] = __builtin_amdgcn_mfma_f32_32x32x16_bf16(pf2, vf2, acc[hh], 0, 0, 0);
    }
  }
  // epilogue: normalize by 1/l (broadcast per output row) and store
#pragma unroll
  for (int hh = 0; hh < 2; ++hh) {
    const float inv = 1.0f / l_[hh];
#pragma unroll
    for (int j = 0; j < 16; ++j) {
      const int pj = (j & 3) + 8 * (j >> 2) + half * 4;
      const float invj = __shfl(inv, pj, 64);
      const int p = p0 + pj;
      if (p < PP && lp < 16)
        ao[((size_t)b * PP + p) * 256 + (h0 + hh) * 16 + lp] = acc[hh][j] * invj;
    }
  }
}

// ---------------------------------------------------------------------------
// score2 = mh @ nodes^T per batch, epilogue 10*tanh(x/16). NT GEMM 64x64.
// ---------------------------------------------------------------------------
__global__ __launch_bounds__(256) void score2_kernel(
    const float* __restrict__ mh, const float* __restrict__ nodes,
    float* __restrict__ s2) {
  __shared__ float At[16][68];
  __shared__ float Bt[16][68];
  const int t = threadIdx.x;
  const int tx = t & 15, ty = t >> 4;
  const int b = blockIdx.z;
  const int row0 = blockIdx.y * 64, col0 = blockIdx.x * 64;
  const float* Ab = mh + (size_t)b * PP * 256;
  const float* Bb = nodes + (size_t)b * NN * 256;
  float* Cb = s2 + (size_t)b * PP * NN;
  const int lr = t >> 2, lkq = t & 3;
  float c[4][4] = {};
  for (int kc = 0; kc < 16; ++kc) {
    const float4 av = *(const float4*)&Ab[(size_t)imin(row0 + lr, PP - 1) * 256 +
                                          kc * 16 + lkq * 4];
    const float4 bv = *(const float4*)&Bb[(size_t)imin(col0 + lr, NN - 1) * 256 +
                                          kc * 16 + lkq * 4];
    At[lkq * 4 + 0][lr] = av.x;
    At[lkq * 4 + 1][lr] = av.y;
    At[lkq * 4 + 2][lr] = av.z;
    At[lkq * 4 + 3][lr] = av.w;
    Bt[lkq * 4 + 0][lr] = bv.x;
    Bt[lkq * 4 + 1][lr] = bv.y;
    Bt[lkq * 4 + 2][lr] = bv.z;
    Bt[lkq * 4 + 3][lr] = bv.w;
    __syncthreads();
#pragma unroll
    for (int kk = 0; kk < 16; ++kk) {
      const float4 a = *(const float4*)&At[kk][ty * 4];
      const float4 w = *(const float4*)&Bt[kk][tx * 4];
      c[0][0] += a.x * w.x; c[0][1] += a.x * w.y; c[0][2] += a.x * w.z; c[0][3] += a.x * w.w;
      c[1][0] += a.y * w.x; c[1][1] += a.y * w.y; c[1][2] += a.y * w.z; c[1][3] += a.y * w.w;
      c[2][0] += a.z * w.x; c[2][1] += a.z * w.y; c[2][2] += a.z * w.z; c[2][3] += a.z * w.w;
      c[3][0] += a.w * w.x; c[3][1] += a.w * w.y; c[3][2] += a.w * w.z; c[3][3] += a.w * w.w;
    }
    __syncthreads();
  }
#pragma unroll
  for (int i = 0; i < 4; ++i) {
    const int row = row0 + ty * 4 + i;
    if (row < PP) {
      const int col = col0 + tx * 4;
      float o[4];
#pragma unroll
      for (int j = 0; j < 4; ++j) o[j] = 10.0f * tanhf(c[i][j] * 0.0625f);
      if (col + 3 < NN) {
        *(float4*)&Cb[(size_t)row * NN + col] = make_float4(o[0], o[1], o[2], o[3]);
      } else {
#pragma unroll
        for (int j = 0; j < 4; ++j)
          if (col + j < NN) Cb[(size_t)row * NN + col + j] = o[j];
      }
    }
  }
}

// ---------------------------------------------------------------------------
// Row softmax over n of (s2 + mask). One block per (b,p) row.
// ---------------------------------------------------------------------------
__global__ __launch_bounds__(256) void softmax_rows(
    const float* __restrict__ s2, const float* __restrict__ mask,
    float* __restrict__ out) {
  const int row = blockIdx.x;
  const size_t base = (size_t)row * NN;
  const int t = threadIdx.x;
  __shared__ float wm[4], wl[4];
  const bool act = t < 250;
  float v0 = 0.f, v1 = 0.f, v2 = 0.f, v3 = 0.f;
  float m = -3.0e38f, l = 0.f;
  if (act) {
    const float4 a = *(const float4*)&s2[base + 4 * t];
    const float4 bq = *(const float4*)&mask[base + 4 * t];
    v0 = a.x + bq.x; v1 = a.y + bq.y; v2 = a.z + bq.z; v3 = a.w + bq.w;
    m = fmaxf(fmaxf(v0, v1), fmaxf(v2, v3));
    l = __expf(v0 - m) + __expf(v1 - m) + __expf(v2 - m) + __expf(v3 - m);
  }
#pragma unroll
  for (int off = 1; off < 64; off <<= 1) {
    const float om = __shfl_xor(m, off, 64);
    const float ol = __shfl_xor(l, off, 64);
    const float nm = fmaxf(m, om);
    l = l * __expf(m - nm) + ol * __expf(om - nm);
    m = nm;
  }
  if ((t & 63) == 0) { wm[t >> 6] = m; wl[t >> 6] = l; }
  __syncthreads();
  float fm = wm[0], fl = wl[0];
#pragma unroll
  for (int w = 1; w < 4; ++w) {
    const float om = wm[w], ol = wl[w];
    const float nm = fmaxf(fm, om);
    fl = fl * __expf(fm - nm) + ol * __expf(om - nm);
    fm = nm;
  }
  if (act) {
    const float inv = 1.0f / fl;
    *(float4*)&out[base + 4 * t] =
        make_float4(__expf(v0 - fm) * inv, __expf(v1 - fm) * inv,
                    __expf(v2 - fm) * inv, __expf(v3 - fm) * inv);
  }
}

// ---------------------------------------------------------------------------
extern "C" void kernel_launch(void* const* d_in, const int* in_sizes, int n_in,
                              void* d_out, int out_size, void* d_ws,
                              size_t ws_size, hipStream_t stream) {
  const float* last  = (const float*)d_in[0];
  const float* attr  = (const float*)d_in[1];
  const float* mask  = (const float*)d_in[2];
  const float* nodes = (const float*)d_in[3];
  const float* Wq    = (const float*)d_in[4];
  const float* Wk    = (const float*)d_in[5];
  const float* Wv    = (const float*)d_in[6];
  const float* Wc    = (const float*)d_in[7];
  const float* bc    = (const float*)d_in[8];
  float* out = (float*)d_out;

  char* base = (char*)d_ws;
  ushort* qbb = (ushort*)(base);                    //  8,388,608 B
  ushort* kbb = (ushort*)(base + 8388608);          //  8,388,608 B
  ushort* vtb = (ushort*)(base + 16777216);         //  8,388,608 B
  float*  vb  = (float*)(base + 25165824);          // 16,384,000 B
  float*  aob = (float*)(base + 41549824);          // 16,384,000 B
  float*  mhb = (float*)(base + 57933824);          // 16,384,000 B
  float*  s2b = (float*)(base + 74317824);          // 64,000,000 B

  const dim3 blk(256);
  const dim3 gg(4, 250);
  gemm256_kernel<3><<<gg, blk, 0, stream>>>(nodes, Wk, nullptr, kbb, nullptr, nullptr);
  gemm256_kernel<0><<<gg, blk, 0, stream>>>(nodes, Wv, vb, nullptr, nullptr, nullptr);
  gemm256_kernel<1><<<gg, blk, 0, stream>>>(last, Wq, nullptr, qbb, attr, Wq + 256 * 256);
  vtrans_kernel<<<dim3(16, 4, 16), blk, 0, stream>>>(vb, vtb);
  attn_mfma2<<<dim3(32, 16), dim3(512), 0, stream>>>(qbb, kbb, vtb, mask, aob);
  gemm256_kernel<2><<<gg, blk, 0, stream>>>(aob, Wc, mhb, nullptr, nullptr, bc);
  score2_kernel<<<dim3(16, 16, 16), blk, 0, stream>>>(mhb, nodes, s2b);
  softmax_rows<<<dim3(16000), blk, 0, stream>>>(s2b, mask, out);
}

// Round 5
// 505.838 us; speedup vs baseline: 4.2769x; 1.0299x over previous
//
#include <hip/hip_runtime.h>
#include <math.h>

#define BB 16
#define PP 1000
#define NN 1000

typedef short bf16x8 __attribute__((ext_vector_type(8)));
typedef float f32x4 __attribute__((ext_vector_type(4)));
typedef float f32x16 __attribute__((ext_vector_type(16)));
typedef unsigned u32x4 __attribute__((ext_vector_type(4)));

static __device__ __forceinline__ int imin(int a, int b) { return a < b ? a : b; }

static __device__ __forceinline__ ushort f2bf(float f) {
  unsigned u = __builtin_bit_cast(unsigned, f);
  u = (u + 0x7FFFu + ((u >> 16) & 1u)) >> 16;
  return (ushort)u;
}
static __device__ __forceinline__ unsigned cvt_pk_bf16(float lo, float hi) {
  unsigned r;
  asm("v_cvt_pk_bf16_f32 %0, %1, %2" : "=v"(r) : "v"(lo), "v"(hi));
  return r;
}

// ---------------------------------------------------------------------------
// GEMM: C[M x 256] = A[M x 256] @ W[256 x 256]  (M = 16000 = 16 b x 1000 rows)
// MODE 0: f32 out (V)        MODE 1: + attr rank-1, bf16 padded out (Q)
// MODE 2: + bias, bf16 padded out (mh)   MODE 3: bf16 padded out (K)
// ---------------------------------------------------------------------------
template <int MODE>
__global__ __launch_bounds__(256) void gemm256_kernel(
    const float* __restrict__ A, const float* __restrict__ W,
    float* __restrict__ C, ushort* __restrict__ Cb,
    const float* __restrict__ ex1, const float* __restrict__ ex2) {
  __shared__ float At[16][68];
  __shared__ float Ws[16][68];
  const int t = threadIdx.x;
  const int tx = t & 15, ty = t >> 4;
  const int row0 = blockIdx.y * 64, col0 = blockIdx.x * 64;
  const int ar = t >> 2, akq = t & 3;
  const int wr = t >> 4, wc = t & 15;
  float c[4][4] = {};
  for (int kc = 0; kc < 16; ++kc) {
    const float4 av =
        *(const float4*)&A[(size_t)(row0 + ar) * 256 + kc * 16 + akq * 4];
    const float4 wv =
        *(const float4*)&W[(size_t)(kc * 16 + wr) * 256 + col0 + wc * 4];
    At[akq * 4 + 0][ar] = av.x;
    At[akq * 4 + 1][ar] = av.y;
    At[akq * 4 + 2][ar] = av.z;
    At[akq * 4 + 3][ar] = av.w;
    *(float4*)&Ws[wr][wc * 4] = wv;
    __syncthreads();
#pragma unroll
    for (int kk = 0; kk < 16; ++kk) {
      const float4 a = *(const float4*)&At[kk][ty * 4];
      const float4 w = *(const float4*)&Ws[kk][tx * 4];
      c[0][0] += a.x * w.x; c[0][1] += a.x * w.y; c[0][2] += a.x * w.z; c[0][3] += a.x * w.w;
      c[1][0] += a.y * w.x; c[1][1] += a.y * w.y; c[1][2] += a.y * w.z; c[1][3] += a.y * w.w;
      c[2][0] += a.z * w.x; c[2][1] += a.z * w.y; c[2][2] += a.z * w.z; c[2][3] += a.z * w.w;
      c[3][0] += a.w * w.x; c[3][1] += a.w * w.y; c[3][2] += a.w * w.z; c[3][3] += a.w * w.w;
    }
    __syncthreads();
  }
#pragma unroll
  for (int i = 0; i < 4; ++i) {
    const int row = row0 + ty * 4 + i;
    const int col = col0 + tx * 4;
    float o0 = c[i][0], o1 = c[i][1], o2 = c[i][2], o3 = c[i][3];
    if (MODE == 1) {
      const float av = ex1[row];
      o0 += av * ex2[col + 0]; o1 += av * ex2[col + 1];
      o2 += av * ex2[col + 2]; o3 += av * ex2[col + 3];
    } else if (MODE == 2) {
      o0 += ex2[col + 0]; o1 += ex2[col + 1];
      o2 += ex2[col + 2]; o3 += ex2[col + 3];
    }
    if (MODE == 0) {
      *(float4*)&C[(size_t)row * 256 + col] = make_float4(o0, o1, o2, o3);
    } else {
      const int b = row / 1000;
      const int p = row - b * 1000;
      ushort4 o;
      o.x = f2bf(o0); o.y = f2bf(o1); o.z = f2bf(o2); o.w = f2bf(o3);
      *(ushort4*)&Cb[((size_t)(b * 1024 + p)) * 256 + col] = o;
    }
  }
}

// ---------------------------------------------------------------------------
// nodes f32 [b][1000][256] -> bf16 padded [b][1024][256]
// ---------------------------------------------------------------------------
__global__ __launch_bounds__(256) void conv_nodes(
    const float* __restrict__ nodes, ushort* __restrict__ nb) {
  const int i = blockIdx.x * 256 + threadIdx.x;  // 512000 threads, 8 elem each
  const int row = i >> 5;
  const int c8 = (i & 31) * 8;
  const int b = row / 1000;
  const int p = row - b * 1000;
  const float4 a0 = *(const float4*)&nodes[(size_t)row * 256 + c8];
  const float4 a1 = *(const float4*)&nodes[(size_t)row * 256 + c8 + 4];
  ushort4 o0, o1;
  o0.x = f2bf(a0.x); o0.y = f2bf(a0.y); o0.z = f2bf(a0.z); o0.w = f2bf(a0.w);
  o1.x = f2bf(a1.x); o1.y = f2bf(a1.y); o1.z = f2bf(a1.z); o1.w = f2bf(a1.w);
  ushort* dst = &nb[((size_t)(b * 1024 + p)) * 256 + c8];
  *(ushort4*)dst = o0;
  *(ushort4*)(dst + 4) = o1;
}

// ---------------------------------------------------------------------------
// V transpose: vb f32 [b][1000][256] -> vt bf16 [b*16+h][16 d][1024 n]
// ---------------------------------------------------------------------------
__global__ __launch_bounds__(256) void vtrans_kernel(
    const float* __restrict__ vb, ushort* __restrict__ vt) {
  __shared__ float T[64][65];
  const int t = threadIdx.x;
  const int b = blockIdx.z;
  const int n0 = blockIdx.x * 64;
  const int c0 = blockIdx.y * 64;
  {
    const int lr = t >> 4;
    const int lc = (t & 15) * 4;
#pragma unroll
    for (int i = 0; i < 4; ++i) {
      const int n_l = lr + i * 16;
      const int row = imin(n0 + n_l, PP - 1);
      const float4 v =
          *(const float4*)&vb[((size_t)b * PP + row) * 256 + c0 + lc];
      T[n_l][lc + 0] = v.x;
      T[n_l][lc + 1] = v.y;
      T[n_l][lc + 2] = v.z;
      T[n_l][lc + 3] = v.w;
    }
  }
  __syncthreads();
  {
    const int n_l = (t & 15) * 4;
#pragma unroll
    for (int i = 0; i < 4; ++i) {
      const int c_l = (t >> 4) + i * 16;
      const int hd = c0 + c_l;
      ushort4 o;
      o.x = f2bf(T[n_l + 0][c_l]);
      o.y = f2bf(T[n_l + 1][c_l]);
      o.z = f2bf(T[n_l + 2][c_l]);
      o.w = f2bf(T[n_l + 3][c_l]);
      *(ushort4*)&vt[((size_t)(b * 16 + (hd >> 4)) * 16 + (hd & 15)) * 1024 +
                     n0 + n_l] = o;
    }
  }
}

// ---------------------------------------------------------------------------
// Swapped-QK^T MFMA attention, 1 head/wave, fixed-base softmax (base 8).
// Block 512 thr (8 waves); grid (32 ptiles, 2 head-halves, 16 b) -> 8192 waves.
// ---------------------------------------------------------------------------
__global__ __launch_bounds__(512) void attn_mfma3(
    const ushort* __restrict__ qb, const ushort* __restrict__ kb,
    const ushort* __restrict__ vt, const float* __restrict__ mask,
    float* __restrict__ ao) {
  const int t = threadIdx.x;
  const int l = t & 63;
  const int w = t >> 6;
  const int lp = l & 31;
  const int half = l >> 5;
  const int b = blockIdx.z;
  const int p0 = blockIdx.x * 32;
  const int h = blockIdx.y * 8 + w;

  const int pm = imin(p0 + lp, PP - 1);
  const float* mrow = &mask[((size_t)b * PP + pm) * NN];

  const bf16x8 qf = *(const bf16x8*)&qb[((size_t)(b * 1024 + p0 + lp)) * 256 +
                                        h * 16 + half * 8];
  const ushort* vrow = &vt[((size_t)((b * 16 + h) * 16 + (lp & 15))) * 1024];

  f32x16 acc;
#pragma unroll
  for (int j = 0; j < 16; ++j) acc[j] = 0.f;
  float l_ = 0.f;

  for (int nt = 0; nt < 32; ++nt) {
    const int n0 = nt * 32;
    // mask, register layout matching C/D rows: reg j <-> n=(j&3)+8*(j>>2)+4*half
    float mqa[16];
    if (nt < 31) {
#pragma unroll
      for (int q = 0; q < 4; ++q) {
        const float4 v = *(const float4*)&mrow[n0 + q * 8 + half * 4];
        mqa[q * 4 + 0] = v.x; mqa[q * 4 + 1] = v.y;
        mqa[q * 4 + 2] = v.z; mqa[q * 4 + 3] = v.w;
      }
    } else {
#pragma unroll
      for (int j = 0; j < 16; ++j) {
        const int nj = n0 + (j & 3) + 8 * (j >> 2) + half * 4;
        mqa[j] = mrow[imin(nj, NN - 1)];
      }
    }
    const bf16x8 kf =
        *(const bf16x8*)&kb[((size_t)(b * 1024 + n0 + lp)) * 256 + h * 16 +
                            half * 8];
    f32x16 cc;
#pragma unroll
    for (int j = 0; j < 16; ++j) cc[j] = 0.f;
    cc = __builtin_amdgcn_mfma_f32_32x32x16_bf16(kf, qf, cc, 0, 0, 0);
    float e[16];
    float ls = 0.f;
#pragma unroll
    for (int j = 0; j < 16; ++j) {
      float s = fmaf(cc[j], 0.25f, mqa[j]);
      if (nt == 31) {
        const int nj = n0 + (j & 3) + 8 * (j >> 2) + half * 4;
        if (nj >= NN) s = -1e30f;
      }
      e[j] = __expf(s - 8.0f);  // fixed-base softmax: exact, no overflow here
      ls += e[j];
    }
    ls += __shfl_xor(ls, 32, 64);
    l_ += ls;
    // pack P to bf16 A-frags (k = local n). Half-exchange via shfl_xor(32).
    unsigned pk0 = cvt_pk_bf16(e[0], e[1]),  pk1 = cvt_pk_bf16(e[2], e[3]);
    unsigned pk2 = cvt_pk_bf16(e[4], e[5]),  pk3 = cvt_pk_bf16(e[6], e[7]);
    unsigned pk4 = cvt_pk_bf16(e[8], e[9]),  pk5 = cvt_pk_bf16(e[10], e[11]);
    unsigned pk6 = cvt_pk_bf16(e[12], e[13]), pk7 = cvt_pk_bf16(e[14], e[15]);
    const unsigned s0 = (unsigned)__shfl_xor((int)pk0, 32, 64);
    const unsigned s1 = (unsigned)__shfl_xor((int)pk1, 32, 64);
    const unsigned s2 = (unsigned)__shfl_xor((int)pk2, 32, 64);
    const unsigned s3 = (unsigned)__shfl_xor((int)pk3, 32, 64);
    const unsigned s4 = (unsigned)__shfl_xor((int)pk4, 32, 64);
    const unsigned s5 = (unsigned)__shfl_xor((int)pk5, 32, 64);
    const unsigned s6 = (unsigned)__shfl_xor((int)pk6, 32, 64);
    const unsigned s7 = (unsigned)__shfl_xor((int)pk7, 32, 64);
    u32x4 w1, w2;
    w1[0] = half ? s2 : pk0;
    w1[1] = half ? s3 : pk1;
    w1[2] = half ? pk2 : s0;
    w1[3] = half ? pk3 : s1;
    w2[0] = half ? s6 : pk4;
    w2[1] = half ? s7 : pk5;
    w2[2] = half ? pk6 : s4;
    w2[3] = half ? pk7 : s5;
    const bf16x8 pf1 = __builtin_bit_cast(bf16x8, w1);
    const bf16x8 pf2 = __builtin_bit_cast(bf16x8, w2);
    const bf16x8 vf1 = *(const bf16x8*)&vrow[n0 + half * 8];
    const bf16x8 vf2 = *(const bf16x8*)&vrow[n0 + 16 + half * 8];
    acc = __builtin_amdgcn_mfma_f32_32x32x16_bf16(pf1, vf1, acc, 0, 0, 0);
    acc = __builtin_amdgcn_mfma_f32_32x32x16_bf16(pf2, vf2, acc, 0, 0, 0);
  }
  const float inv = 1.0f / l_;
#pragma unroll
  for (int j = 0; j < 16; ++j) {
    const int pj = (j & 3) + 8 * (j >> 2) + half * 4;
    const float invj = __shfl(inv, pj, 64);
    const int p = p0 + pj;
    if (p < PP && lp < 16)
      ao[((size_t)b * PP + p) * 256 + h * 16 + lp] = acc[j] * invj;
  }
}

// ---------------------------------------------------------------------------
// score2 MFMA: s2[p][n] = mh[p][:]·nodes[n][:] (NT), epilogue 10*tanh(x/16).
// Block 256 thr (4 waves), 64x64 tile, wave = 32x32 quadrant, K=256 (16 MFMA).
// ---------------------------------------------------------------------------
__global__ __launch_bounds__(256) void score2_mfma(
    const ushort* __restrict__ mhb, const ushort* __restrict__ nodesb,
    float* __restrict__ s2) {
  const int t = threadIdx.x;
  const int w = t >> 6;
  const int l = t & 63;
  const int lp = l & 31;
  const int half = l >> 5;
  const int b = blockIdx.z;
  const int n0 = blockIdx.x * 64 + (w & 1) * 32;
  const int p0 = blockIdx.y * 64 + (w >> 1) * 32;
  const ushort* arow = &mhb[((size_t)(b * 1024 + p0 + lp)) * 256 + half * 8];
  const ushort* brow = &nodesb[((size_t)(b * 1024 + n0 + lp)) * 256 + half * 8];
  f32x16 acc;
#pragma unroll
  for (int j = 0; j < 16; ++j) acc[j] = 0.f;
#pragma unroll
  for (int kt = 0; kt < 16; ++kt) {
    const bf16x8 af = *(const bf16x8*)&arow[kt * 16];
    const bf16x8 bf = *(const bf16x8*)&brow[kt * 16];
    acc = __builtin_amdgcn_mfma_f32_32x32x16_bf16(af, bf, acc, 0, 0, 0);
  }
  const int n = n0 + lp;
  if (n < NN) {
    float* Cb = s2 + (size_t)b * PP * NN;
#pragma unroll
    for (int j = 0; j < 16; ++j) {
      const int p = p0 + (j & 3) + 8 * (j >> 2) + 4 * half;
      if (p < PP) {
        // 10*tanh(c/16) = 10 - 20/(exp(c/8)+1)
        const float E = __expf(acc[j] * 0.125f);
        Cb[(size_t)p * NN + n] = 10.0f - 20.0f / (E + 1.0f);
      }
    }
  }
}

// ---------------------------------------------------------------------------
// Row softmax over n of (s2 + mask). One block per (b,p) row.
// ---------------------------------------------------------------------------
__global__ __launch_bounds__(256) void softmax_rows(
    const float* __restrict__ s2, const float* __restrict__ mask,
    float* __restrict__ out) {
  const int row = blockIdx.x;
  const size_t base = (size_t)row * NN;
  const int t = threadIdx.x;
  __shared__ float wm[4], wl[4];
  const bool act = t < 250;
  float v0 = 0.f, v1 = 0.f, v2 = 0.f, v3 = 0.f;
  float m = -3.0e38f, l = 0.f;
  if (act) {
    const float4 a = *(const float4*)&s2[base + 4 * t];
    const float4 bq = *(const float4*)&mask[base + 4 * t];
    v0 = a.x + bq.x; v1 = a.y + bq.y; v2 = a.z + bq.z; v3 = a.w + bq.w;
    m = fmaxf(fmaxf(v0, v1), fmaxf(v2, v3));
    l = __expf(v0 - m) + __expf(v1 - m) + __expf(v2 - m) + __expf(v3 - m);
  }
#pragma unroll
  for (int off = 1; off < 64; off <<= 1) {
    const float om = __shfl_xor(m, off, 64);
    const float ol = __shfl_xor(l, off, 64);
    const float nm = fmaxf(m, om);
    l = l * __expf(m - nm) + ol * __expf(om - nm);
    m = nm;
  }
  if ((t & 63) == 0) { wm[t >> 6] = m; wl[t >> 6] = l; }
  __syncthreads();
  float fm = wm[0], fl = wl[0];
#pragma unroll
  for (int w = 1; w < 4; ++w) {
    const float om = wm[w], ol = wl[w];
    const float nm = fmaxf(fm, om);
    fl = fl * __expf(fm - nm) + ol * __expf(om - nm);
    fm = nm;
  }
  if (act) {
    const float inv = 1.0f / fl;
    *(float4*)&out[base + 4 * t] =
        make_float4(__expf(v0 - fm) * inv, __expf(v1 - fm) * inv,
                    __expf(v2 - fm) * inv, __expf(v3 - fm) * inv);
  }
}

// ---------------------------------------------------------------------------
extern "C" void kernel_launch(void* const* d_in, const int* in_sizes, int n_in,
                              void* d_out, int out_size, void* d_ws,
                              size_t ws_size, hipStream_t stream) {
  const float* last  = (const float*)d_in[0];
  const float* attr  = (const float*)d_in[1];
  const float* mask  = (const float*)d_in[2];
  const float* nodes = (const float*)d_in[3];
  const float* Wq    = (const float*)d_in[4];
  const float* Wk    = (const float*)d_in[5];
  const float* Wv    = (const float*)d_in[6];
  const float* Wc    = (const float*)d_in[7];
  const float* bc    = (const float*)d_in[8];
  float* out = (float*)d_out;

  char* base = (char*)d_ws;
  ushort* qbb  = (ushort*)(base);                   //  8,388,608 B
  ushort* kbb  = (ushort*)(base + 8388608);         //  8,388,608 B
  ushort* vtb  = (ushort*)(base + 16777216);        //  8,388,608 B
  float*  vb   = (float*)(base + 25165824);         // 16,384,000 B
  ushort* mbb  = (ushort*)(base + 41549824);        //  8,388,608 B
  ushort* ndb  = (ushort*)(base + 49938432);        //  8,388,608 B
  float*  aob  = (float*)(base + 58327040);         // 16,384,000 B
  float*  s2b  = (float*)(base + 74711040);         // 64,000,000 B -> 138.7 MB

  const dim3 blk(256);
  const dim3 gg(4, 250);
  gemm256_kernel<3><<<gg, blk, 0, stream>>>(nodes, Wk, nullptr, kbb, nullptr, nullptr);
  gemm256_kernel<0><<<gg, blk, 0, stream>>>(nodes, Wv, vb, nullptr, nullptr, nullptr);
  gemm256_kernel<1><<<gg, blk, 0, stream>>>(last, Wq, nullptr, qbb, attr, Wq + 256 * 256);
  vtrans_kernel<<<dim3(16, 4, 16), blk, 0, stream>>>(vb, vtb);
  conv_nodes<<<dim3(2000), blk, 0, stream>>>(nodes, ndb);
  attn_mfma3<<<dim3(32, 2, 16), dim3(512), 0, stream>>>(qbb, kbb, vtb, mask, aob);
  gemm256_kernel<2><<<gg, blk, 0, stream>>>(aob, Wc, nullptr, mbb, nullptr, bc);
  score2_mfma<<<dim3(16, 16, 16), blk, 0, stream>>>(mbb, ndb, s2b);
  softmax_rows<<<dim3(16000), blk, 0, stream>>>(s2b, mask, out);
}

// Round 7
// 412.664 us; speedup vs baseline: 5.2425x; 1.2258x over previous
//
#include <hip/hip_runtime.h>
#include <math.h>

#define PP 1000
#define NN 1000

typedef short bf16x8 __attribute__((ext_vector_type(8)));
typedef float f32x16 __attribute__((ext_vector_type(16)));
typedef unsigned u32x4 __attribute__((ext_vector_type(4)));

static __device__ __forceinline__ int imin(int a, int b) { return a < b ? a : b; }

static __device__ __forceinline__ ushort f2bf(float f) {
  unsigned u = __builtin_bit_cast(unsigned, f);
  u = (u + 0x7FFFu + ((u >> 16) & 1u)) >> 16;
  return (ushort)u;
}
static __device__ __forceinline__ unsigned cvt_pk_bf16(float lo, float hi) {
  unsigned r;
  asm("v_cvt_pk_bf16_f32 %0, %1, %2" : "=v"(r) : "v"(lo), "v"(hi));
  return r;
}

// D row index for mfma_32x32x16 reg j (half = lane>>5)
#define ROWF(j, half) (((j) & 3) + 8 * ((j) >> 2) + 4 * (half))

// ---------------------------------------------------------------------------
// f32 [16*1000][256] -> bf16 padded [16*1024][256]
// ---------------------------------------------------------------------------
__global__ __launch_bounds__(256) void conv_pad(const float* __restrict__ src,
                                                ushort* __restrict__ dst) {
  const int i = blockIdx.x * 256 + threadIdx.x;  // 512000 threads, 8 elems each
  const int row = i >> 5;
  const int c8 = (i & 31) * 8;
  const int b = row / 1000;
  const int p = row - b * 1000;
  const float4 a0 = *(const float4*)&src[(size_t)row * 256 + c8];
  const float4 a1 = *(const float4*)&src[(size_t)row * 256 + c8 + 4];
  ushort4 o0, o1;
  o0.x = f2bf(a0.x); o0.y = f2bf(a0.y); o0.z = f2bf(a0.z); o0.w = f2bf(a0.w);
  o1.x = f2bf(a1.x); o1.y = f2bf(a1.y); o1.z = f2bf(a1.z); o1.w = f2bf(a1.w);
  ushort* d = &dst[((size_t)(b * 1024 + p)) * 256 + c8];
  *(ushort4*)d = o0;
  *(ushort4*)(d + 4) = o1;
}

// ---------------------------------------------------------------------------
// Weight transpose+convert: W f32 [256 k][256 c] -> Wt bf16 [256 c][256 k]
// ---------------------------------------------------------------------------
__global__ __launch_bounds__(256) void conv_w(
    const float* __restrict__ w0, const float* __restrict__ w1,
    const float* __restrict__ w2, const float* __restrict__ w3,
    ushort* __restrict__ t0, ushort* __restrict__ t1,
    ushort* __restrict__ t2, ushort* __restrict__ t3) {
  const float* srcs[4] = {w0, w1, w2, w3};
  ushort* dsts[4] = {t0, t1, t2, t3};
  const float* W = srcs[blockIdx.y];
  ushort* T = dsts[blockIdx.y];
  __shared__ float L[64][65];
  const int t = threadIdx.x;
  const int k0 = (blockIdx.x & 3) * 64, c0 = (blockIdx.x >> 2) * 64;
#pragma unroll
  for (int i = 0; i < 4; ++i) {
    const int kr = (t >> 4) + i * 16;
    const int cq = (t & 15) * 4;
    const float4 v = *(const float4*)&W[(size_t)(k0 + kr) * 256 + c0 + cq];
    L[kr][cq + 0] = v.x; L[kr][cq + 1] = v.y;
    L[kr][cq + 2] = v.z; L[kr][cq + 3] = v.w;
  }
  __syncthreads();
#pragma unroll
  for (int i = 0; i < 4; ++i) {
    const int cl = (t >> 4) + i * 16;
    const int kq = (t & 15) * 4;
    ushort4 o;
    o.x = f2bf(L[kq + 0][cl]); o.y = f2bf(L[kq + 1][cl]);
    o.z = f2bf(L[kq + 2][cl]); o.w = f2bf(L[kq + 3][cl]);
    *(ushort4*)&T[(size_t)(c0 + cl) * 256 + k0 + kq] = o;
  }
}

// ---------------------------------------------------------------------------
// MFMA projection: C[p][c] = sum_k A[p][k] * Wt[c][k]   (A bf16 padded rows)
// block 256 (4 waves), tile 64p x 64c, wave = 32x32, K=256 -> 16 MFMA.
// MODE 0: flat bf16 padded out [b*1024][256]            (K)
// MODE 1: flat + attr[p]*wql[c] rank-1                  (Q)
// MODE 2: flat + bias                                   (mh)
// MODE 3: rows are n; out vt [b][16h][16d][1024n]       (V)
// ---------------------------------------------------------------------------
template <int MODE>
__global__ __launch_bounds__(256) void proj_mfma(
    const ushort* __restrict__ A, const ushort* __restrict__ Wt,
    ushort* __restrict__ out, const float* __restrict__ ex1,
    const float* __restrict__ ex2) {
  const int t = threadIdx.x;
  const int w = t >> 6, l = t & 63;
  const int lp = l & 31, half = l >> 5;
  const int b = blockIdx.z;
  const int c0 = blockIdx.x * 64 + (w & 1) * 32;
  const int p0 = blockIdx.y * 64 + (w >> 1) * 32;
  const ushort* arow =
      &A[((size_t)(b * 1024 + imin(p0 + lp, PP - 1))) * 256 + half * 8];
  const ushort* brow = &Wt[(size_t)(c0 + lp) * 256 + half * 8];
  f32x16 acc;
#pragma unroll
  for (int j = 0; j < 16; ++j) acc[j] = 0.f;
#pragma unroll
  for (int kt = 0; kt < 16; ++kt) {
    const bf16x8 af = *(const bf16x8*)&arow[kt * 16];
    const bf16x8 bf = *(const bf16x8*)&brow[kt * 16];
    acc = __builtin_amdgcn_mfma_f32_32x32x16_bf16(af, bf, acc, 0, 0, 0);
  }
  const int c = c0 + lp;
  if (MODE == 1) {
    const float wq = ex2[c];
#pragma unroll
    for (int j = 0; j < 16; ++j) {
      const int p = p0 + ROWF(j, half);
      acc[j] += ex1[b * 1000 + imin(p, PP - 1)] * wq;
    }
  }
  if (MODE == 2) {
    const float bias = ex2[c];
#pragma unroll
    for (int j = 0; j < 16; ++j) acc[j] += bias;
  }
  if (MODE == 3) {  // rows=n, write transposed into vt
    const int h = c >> 4, d = c & 15;
    ushort* vr = &out[((size_t)((b * 16 + h) * 16 + d)) * 1024];
#pragma unroll
    for (int q = 0; q < 4; ++q) {
      ushort4 o;
      o.x = f2bf(acc[4 * q + 0]); o.y = f2bf(acc[4 * q + 1]);
      o.z = f2bf(acc[4 * q + 2]); o.w = f2bf(acc[4 * q + 3]);
      *(ushort4*)&vr[p0 + 8 * q + 4 * half] = o;
    }
  } else {
#pragma unroll
    for (int j = 0; j < 16; ++j) {
      const int p = p0 + ROWF(j, half);
      out[((size_t)(b * 1024 + p)) * 256 + c] = f2bf(acc[j]);
    }
  }
}

// ---------------------------------------------------------------------------
// Swapped-QK^T MFMA attention (round-4 version, verbatim — known good).
// Block = 512 thr (8 waves), grid (32 ptiles, 16 b). Wave w: heads 2w, 2w+1.
// ---------------------------------------------------------------------------
__global__ __launch_bounds__(512) void attn_mfma2(
    const ushort* __restrict__ qb, const ushort* __restrict__ kb,
    const ushort* __restrict__ vt, const float* __restrict__ mask,
    float* __restrict__ ao) {
  const int t = threadIdx.x;
  const int l = t & 63;
  const int w = t >> 6;      // wave 0..7
  const int lp = l & 31;     // p-col (QK out) / n-row (K frag) lane index
  const int half = l >> 5;
  const int b = blockIdx.y;
  const int p0 = blockIdx.x * 32;
  const int h0 = w * 2;

  const int pm = imin(p0 + lp, PP - 1);
  const float* mrow = &mask[((size_t)b * PP + pm) * NN];

  bf16x8 qf[2];
#pragma unroll
  for (int hh = 0; hh < 2; ++hh)
    qf[hh] = *(const bf16x8*)&qb[((size_t)(b * 1024 + p0 + lp)) * 256 +
                                 (h0 + hh) * 16 + half * 8];

  f32x16 acc[2];
  float m_[2] = {-1e30f, -1e30f};
  float l_[2] = {0.f, 0.f};
#pragma unroll
  for (int hh = 0; hh < 2; ++hh)
#pragma unroll
    for (int j = 0; j < 16; ++j) acc[hh][j] = 0.f;

  for (int nt = 0; nt < 32; ++nt) {
    const int n0 = nt * 32;
    // mask values, register layout matching C/D rows: reg j <-> n = ROWF(j,half)
    float mqa[16];
    if (nt < 31) {
#pragma unroll
      for (int q = 0; q < 4; ++q) {
        const float4 v = *(const float4*)&mrow[n0 + q * 8 + half * 4];
        mqa[q * 4 + 0] = v.x; mqa[q * 4 + 1] = v.y;
        mqa[q * 4 + 2] = v.z; mqa[q * 4 + 3] = v.w;
      }
    } else {
#pragma unroll
      for (int j = 0; j < 16; ++j) {
        const int nj = n0 + ROWF(j, half);
        mqa[j] = mrow[imin(nj, NN - 1)];
      }
    }
#pragma unroll
    for (int hh = 0; hh < 2; ++hh) {
      const int h = h0 + hh;
      const bf16x8 kf =
          *(const bf16x8*)&kb[((size_t)(b * 1024 + n0 + lp)) * 256 + h * 16 +
                              half * 8];
      f32x16 cc;
#pragma unroll
      for (int j = 0; j < 16; ++j) cc[j] = 0.f;
      cc = __builtin_amdgcn_mfma_f32_32x32x16_bf16(kf, qf[hh], cc, 0, 0, 0);
      float s[16];
#pragma unroll
      for (int j = 0; j < 16; ++j) s[j] = fmaf(cc[j], 0.25f, mqa[j]);
      if (nt == 31) {
#pragma unroll
        for (int j = 0; j < 16; ++j) {
          const int nj = n0 + ROWF(j, half);
          if (nj >= NN) s[j] = -1e30f;
        }
      }
      // chunk max (lane-local + cross-half)
      float pmax = s[0];
#pragma unroll
      for (int j = 1; j < 16; ++j) pmax = fmaxf(pmax, s[j]);
      pmax = fmaxf(pmax, __shfl_xor(pmax, 32, 64));
      // defer-max: rescale only when the running base is stale by >8
      if (!__all(pmax <= m_[hh] + 8.0f)) {
        const float mnew = fmaxf(m_[hh], pmax);
        const float f = __expf(m_[hh] - mnew);
        m_[hh] = mnew;
        l_[hh] *= f;
#pragma unroll
        for (int j = 0; j < 16; ++j) {
          const int pj = ROWF(j, half);
          const float fj = __shfl(f, pj, 64);
          acc[hh][j] *= fj;
        }
      }
      // exp + sum
      float e[16];
      float ls = 0.f;
#pragma unroll
      for (int j = 0; j < 16; ++j) {
        e[j] = __expf(s[j] - m_[hh]);
        ls += e[j];
      }
      ls += __shfl_xor(ls, 32, 64);
      l_[hh] += ls;
      // pack P to bf16 A-frags (k = n_local). Half-exchange via shfl_xor(32).
      unsigned pk0 = cvt_pk_bf16(e[0], e[1]),  pk1 = cvt_pk_bf16(e[2], e[3]);
      unsigned pk2 = cvt_pk_bf16(e[4], e[5]),  pk3 = cvt_pk_bf16(e[6], e[7]);
      unsigned pk4 = cvt_pk_bf16(e[8], e[9]),  pk5 = cvt_pk_bf16(e[10], e[11]);
      unsigned pk6 = cvt_pk_bf16(e[12], e[13]), pk7 = cvt_pk_bf16(e[14], e[15]);
      const unsigned s0 = (unsigned)__shfl_xor((int)pk0, 32, 64);
      const unsigned s2 = (unsigned)__shfl_xor((int)pk2, 32, 64);
      const unsigned s1 = (unsigned)__shfl_xor((int)pk1, 32, 64);
      const unsigned s3 = (unsigned)__shfl_xor((int)pk3, 32, 64);
      const unsigned s4 = (unsigned)__shfl_xor((int)pk4, 32, 64);
      const unsigned s6 = (unsigned)__shfl_xor((int)pk6, 32, 64);
      const unsigned s5 = (unsigned)__shfl_xor((int)pk5, 32, 64);
      const unsigned s7 = (unsigned)__shfl_xor((int)pk7, 32, 64);
      u32x4 w1, w2;
      w1[0] = half ? s2 : pk0;  // k 0,1   | 8,9
      w1[1] = half ? s3 : pk1;  // k 2,3   | 10,11
      w1[2] = half ? pk2 : s0;  // k 4,5   | 12,13
      w1[3] = half ? pk3 : s1;  // k 6,7   | 14,15
      w2[0] = half ? s6 : pk4;  // k 16,17 | 24,25
      w2[1] = half ? s7 : pk5;  // k 18,19 | 26,27
      w2[2] = half ? pk6 : s4;  // k 20,21 | 28,29
      w2[3] = half ? pk7 : s5;  // k 22,23 | 30,31
      const bf16x8 pf1 = __builtin_bit_cast(bf16x8, w1);
      const bf16x8 pf2 = __builtin_bit_cast(bf16x8, w2);
      const ushort* vrow =
          &vt[((size_t)((b * 16 + h) * 16 + (lp & 15))) * 1024];
      const bf16x8 vf1 = *(const bf16x8*)&vrow[n0 + half * 8];
      const bf16x8 vf2 = *(const bf16x8*)&vrow[n0 + 16 + half * 8];
      acc[hh] = __builtin_amdgcn_mfma_f32_32x32x16_bf16(pf1, vf1, acc[hh], 0, 0, 0);
      acc[hh] = __builtin_amdgcn_mfma_f32_32x32x16_bf16(pf2, vf2, acc[hh], 0, 0, 0);
    }
  }
  // epilogue: normalize by 1/l (broadcast per output row) and store
#pragma unroll
  for (int hh = 0; hh < 2; ++hh) {
    const float inv = 1.0f / l_[hh];
#pragma unroll
    for (int j = 0; j < 16; ++j) {
      const int pj = ROWF(j, half);
      const float invj = __shfl(inv, pj, 64);
      const int p = p0 + pj;
      if (p < PP && lp < 16)
        ao[((size_t)b * PP + p) * 256 + (h0 + hh) * 16 + lp] = acc[hh][j] * invj;
    }
  }
}

// ---------------------------------------------------------------------------
// Fused score2 + clip-tanh + mask + row-softmax.
// Block 512 (8 waves), grid (32 ptiles of 32, 16 b). Wave w: n in [w*128,+128).
// ---------------------------------------------------------------------------
__global__ __launch_bounds__(512, 1) void fused_probe(
    const ushort* __restrict__ ndb, const ushort* __restrict__ mbb,
    const float* __restrict__ mask, float* __restrict__ out) {
  __shared__ float smax[8][32];
  __shared__ float ssum[8][32];
  const int t = threadIdx.x;
  const int l = t & 63, w = t >> 6;
  const int lp = l & 31, half = l >> 5;
  const int b = blockIdx.y;
  const int p0 = blockIdx.x * 32;

  const ushort* brow = &mbb[((size_t)(b * 1024 + p0 + lp)) * 256 + half * 8];
  f32x16 acc[4];
#pragma unroll
  for (int tt = 0; tt < 4; ++tt)
#pragma unroll
    for (int j = 0; j < 16; ++j) acc[tt][j] = 0.f;

#pragma unroll
  for (int tt = 0; tt < 4; ++tt) {
    const int n = imin(w * 128 + tt * 32 + lp, NN - 1);
    const ushort* arow = &ndb[((size_t)(b * 1024 + n)) * 256 + half * 8];
#pragma unroll
    for (int kt = 0; kt < 16; ++kt) {
      const bf16x8 af = *(const bf16x8*)&arow[kt * 16];
      const bf16x8 bf = *(const bf16x8*)&brow[kt * 16];
      acc[tt] = __builtin_amdgcn_mfma_f32_32x32x16_bf16(af, bf, acc[tt], 0, 0, 0);
    }
  }
  // epilogue: clip-tanh + mask, lane-local max
  const float* mrow2 = &mask[((size_t)b * PP + imin(p0 + lp, PP - 1)) * NN];
  float vmax = -1e30f;
#pragma unroll
  for (int tt = 0; tt < 4; ++tt) {
#pragma unroll
    for (int q = 0; q < 4; ++q) {
      const int nb = w * 128 + tt * 32 + 8 * q + 4 * half;
      float4 mv = make_float4(0.f, 0.f, 0.f, 0.f);
      if (nb < NN) mv = *(const float4*)&mrow2[nb];
#pragma unroll
      for (int r = 0; r < 4; ++r) {
        const int j = 4 * q + r;
        const float E = __expf(acc[tt][j] * 0.125f);
        float v = 10.0f - 20.0f / (E + 1.0f);
        v += (r == 0 ? mv.x : r == 1 ? mv.y : r == 2 ? mv.z : mv.w);
        if (nb + r >= NN) v = -1e30f;
        acc[tt][j] = v;
        vmax = fmaxf(vmax, v);
      }
    }
  }
  vmax = fmaxf(vmax, __shfl_xor(vmax, 32, 64));
  if (half == 0) smax[w][lp] = vmax;
  __syncthreads();
  float mg = smax[0][lp];
#pragma unroll
  for (int ww = 1; ww < 8; ++ww) mg = fmaxf(mg, smax[ww][lp]);
  float lsum = 0.f;
#pragma unroll
  for (int tt = 0; tt < 4; ++tt)
#pragma unroll
    for (int j = 0; j < 16; ++j) {
      const float e = __expf(acc[tt][j] - mg);
      acc[tt][j] = e;
      lsum += e;
    }
  lsum += __shfl_xor(lsum, 32, 64);
  if (half == 0) ssum[w][lp] = lsum;
  __syncthreads();
  float lt = 0.f;
#pragma unroll
  for (int ww = 0; ww < 8; ++ww) lt += ssum[ww][lp];
  const float inv = 1.0f / lt;
  const int p = p0 + lp;
  if (p < PP) {
    float* orow = &out[((size_t)b * PP + p) * NN];
#pragma unroll
    for (int tt = 0; tt < 4; ++tt)
#pragma unroll
      for (int q = 0; q < 4; ++q) {
        const int nb = w * 128 + tt * 32 + 8 * q + 4 * half;
        if (nb < NN)
          *(float4*)&orow[nb] =
              make_float4(acc[tt][4 * q + 0] * inv, acc[tt][4 * q + 1] * inv,
                          acc[tt][4 * q + 2] * inv, acc[tt][4 * q + 3] * inv);
      }
  }
}

// ---------------------------------------------------------------------------
extern "C" void kernel_launch(void* const* d_in, const int* in_sizes, int n_in,
                              void* d_out, int out_size, void* d_ws,
                              size_t ws_size, hipStream_t stream) {
  const float* last  = (const float*)d_in[0];
  const float* attr  = (const float*)d_in[1];
  const float* mask  = (const float*)d_in[2];
  const float* nodes = (const float*)d_in[3];
  const float* Wq    = (const float*)d_in[4];
  const float* Wk    = (const float*)d_in[5];
  const float* Wv    = (const float*)d_in[6];
  const float* Wc    = (const float*)d_in[7];
  const float* bc    = (const float*)d_in[8];
  float* out = (float*)d_out;

  char* base = (char*)d_ws;
  ushort* ndb = (ushort*)(base);               //  8,388,608
  ushort* ldb = (ushort*)(base + 8388608);     //  8,388,608
  ushort* kbb = (ushort*)(base + 16777216);    //  8,388,608
  ushort* qbb = (ushort*)(base + 25165824);    //  8,388,608
  ushort* vtb = (ushort*)(base + 33554432);    //  8,388,608
  float*  aof = (float*)(base + 41943040);     // 16,384,000
  ushort* aob = (ushort*)(base + 58327040);    //  8,388,608
  ushort* mbb = (ushort*)(base + 66715648);    //  8,388,608
  ushort* wkt = (ushort*)(base + 75104256);    //    131,072
  ushort* wvt = (ushort*)(base + 75235328);    //    131,072
  ushort* wqt = (ushort*)(base + 75366400);    //    131,072
  ushort* wct = (ushort*)(base + 75497472);    //    131,072  (~72.1 MB)

  const dim3 blk(256);
  conv_w<<<dim3(16, 4), blk, 0, stream>>>(Wk, Wv, Wq, Wc, wkt, wvt, wqt, wct);
  conv_pad<<<dim3(2000), blk, 0, stream>>>(nodes, ndb);
  conv_pad<<<dim3(2000), blk, 0, stream>>>(last, ldb);
  proj_mfma<0><<<dim3(4, 16, 16), blk, 0, stream>>>(ndb, wkt, kbb, nullptr, nullptr);
  proj_mfma<1><<<dim3(4, 16, 16), blk, 0, stream>>>(ldb, wqt, qbb, attr, Wq + 256 * 256);
  proj_mfma<3><<<dim3(4, 16, 16), blk, 0, stream>>>(ndb, wvt, vtb, nullptr, nullptr);
  attn_mfma2<<<dim3(32, 16), dim3(512), 0, stream>>>(qbb, kbb, vtb, mask, aof);
  conv_pad<<<dim3(2000), blk, 0, stream>>>(aof, aob);
  proj_mfma<2><<<dim3(4, 16, 16), blk, 0, stream>>>(aob, wct, mbb, nullptr, bc);
  fused_probe<<<dim3(32, 16), dim3(512), 0, stream>>>(ndb, mbb, mask, out);
}